// Round 1
// baseline (3108.520 us; speedup 1.0000x reference)
//
#include <hip/hip_runtime.h>
#include <math.h>

#define K_ADA 0.1f
#define NEPS 1e-5f

__device__ __forceinline__ float wave_sum64(float v) {
#pragma unroll
    for (int m = 1; m < 64; m <<= 1) v += __shfl_xor(v, m, 64);
    return v;
}

// Generic fused sparse conv3d (k=3, pad=1) + optional AdaNorm+ReLU when CPT==COUT.
// Thread t handles voxel v = t/NG, cout range [g*CPT, (g+1)*CPT) with g = t%NG.
template <int GOUT, int GIN, int CIN, int COUT, int CPT, int STRIDE>
__global__ __launch_bounds__(256) void conv_k(
    const float* __restrict__ hin, const float* __restrict__ m_in,
    const float* __restrict__ m_out, const float* __restrict__ w,
    const float* __restrict__ bias, const float* __restrict__ gain,
    float* __restrict__ hout)
{
    constexpr int NG = COUT / CPT;
    constexpr int NVOX = 2 * GOUT * GOUT * GOUT;
    int t = blockIdx.x * 256 + threadIdx.x;
    if (t >= NVOX * NG) return;
    int g = t % NG;
    int v = t / NG;
    int b = v / (GOUT * GOUT * GOUT);
    int r = v % (GOUT * GOUT * GOUT);
    int d = r / (GOUT * GOUT);
    int hh = (r / GOUT) % GOUT;
    int x = r % GOUT;

    float* outp = hout + (size_t)v * COUT + g * CPT;
    if (m_out[v] == 0.f) {
#pragma unroll
        for (int i = 0; i < CPT / 4; ++i)
            reinterpret_cast<float4*>(outp)[i] = make_float4(0.f, 0.f, 0.f, 0.f);
        return;
    }

    float acc[CPT];
#pragma unroll
    for (int i = 0; i < CPT; ++i) acc[i] = bias[g * CPT + i];

    for (int kd = 0; kd < 3; ++kd) {
        int zd = d * STRIDE + kd - 1;
        if (zd < 0 || zd >= GIN) continue;
        for (int kh = 0; kh < 3; ++kh) {
            int zh = hh * STRIDE + kh - 1;
            if (zh < 0 || zh >= GIN) continue;
            for (int kw = 0; kw < 3; ++kw) {
                int zx = x * STRIDE + kw - 1;
                if (zx < 0 || zx >= GIN) continue;
                int nv = ((b * GIN + zd) * GIN + zh) * GIN + zx;
                if (m_in[nv] == 0.f) continue;  // zero input voxel: exact skip
                const float* ip = hin + (size_t)nv * CIN;
                const float* wp = w + ((kd * 3 + kh) * 3 + kw) * (CIN * COUT) + g * CPT;
                if constexpr (CIN == 1) {
                    float iv = ip[0];
#pragma unroll
                    for (int c4 = 0; c4 < CPT / 4; ++c4) {
                        float4 wv = *reinterpret_cast<const float4*>(wp + c4 * 4);
                        acc[c4 * 4 + 0] += iv * wv.x;
                        acc[c4 * 4 + 1] += iv * wv.y;
                        acc[c4 * 4 + 2] += iv * wv.z;
                        acc[c4 * 4 + 3] += iv * wv.w;
                    }
                } else {
#pragma unroll
                    for (int ci4 = 0; ci4 < CIN / 4; ++ci4) {
                        float4 iv = reinterpret_cast<const float4*>(ip)[ci4];
                        float ivs[4] = {iv.x, iv.y, iv.z, iv.w};
#pragma unroll
                        for (int j = 0; j < 4; ++j) {
                            const float* wr = wp + (ci4 * 4 + j) * COUT;
#pragma unroll
                            for (int c4 = 0; c4 < CPT / 4; ++c4) {
                                float4 wv = *reinterpret_cast<const float4*>(wr + c4 * 4);
                                acc[c4 * 4 + 0] += ivs[j] * wv.x;
                                acc[c4 * 4 + 1] += ivs[j] * wv.y;
                                acc[c4 * 4 + 2] += ivs[j] * wv.z;
                                acc[c4 * 4 + 3] += ivs[j] * wv.w;
                            }
                        }
                    }
                }
            }
        }
    }

    if constexpr (CPT == COUT) {  // fused AdaNorm + ReLU (one thread owns the voxel)
        float mean = 0.f;
#pragma unroll
        for (int i = 0; i < COUT; ++i) mean += acc[i];
        mean *= (1.f / COUT);
        float var = 0.f;
#pragma unroll
        for (int i = 0; i < COUT; ++i) { float dd = acc[i] - mean; var += dd * dd; }
        var = var * (1.f / COUT) + NEPS;
        float rs = rsqrtf(var);
#pragma unroll
        for (int i = 0; i < COUT; ++i) {
            float xn = (acc[i] - mean) * rs;
            float val = gain[i] * (1.f - K_ADA * xn) * xn;
            acc[i] = fmaxf(val, 0.f);
        }
    }
#pragma unroll
    for (int c4 = 0; c4 < CPT / 4; ++c4)
        reinterpret_cast<float4*>(outp)[c4] =
            make_float4(acc[c4 * 4], acc[c4 * 4 + 1], acc[c4 * 4 + 2], acc[c4 * 4 + 3]);
}

// AdaNorm+ReLU over 64 channels, in-place; one wave == one voxel (lane == channel).
__global__ __launch_bounds__(256) void norm64_k(float* __restrict__ h,
                                                const float* __restrict__ gain, int n)
{
    int t = blockIdx.x * 256 + threadIdx.x;
    if (t >= n) return;
    float val = h[t];
    int c = t & 63;
    float mean = wave_sum64(val) * (1.f / 64.f);
    float dd = val - mean;
    float var = wave_sum64(dd * dd) * (1.f / 64.f) + NEPS;
    float xn = dd * rsqrtf(var);
    float o = gain[c] * (1.f - K_ADA * xn) * xn;
    h[t] = fmaxf(o, 0.f);
}

// downsample mask: max over 3^3 window, stride 2, pad 1
template <int GO, int GI>
__global__ __launch_bounds__(256) void dmask_k(const float* __restrict__ mi,
                                               float* __restrict__ mo)
{
    constexpr int N = 2 * GO * GO * GO;
    int v = blockIdx.x * 256 + threadIdx.x;
    if (v >= N) return;
    int b = v / (GO * GO * GO);
    int r = v % (GO * GO * GO);
    int d = r / (GO * GO), h = (r / GO) % GO, x = r % GO;
    float mx = 0.f;
    for (int kd = 0; kd < 3; ++kd) {
        int zd = 2 * d + kd - 1;
        if (zd < 0 || zd >= GI) continue;
        for (int kh = 0; kh < 3; ++kh) {
            int zh = 2 * h + kh - 1;
            if (zh < 0 || zh >= GI) continue;
            for (int kw = 0; kw < 3; ++kw) {
                int zx = 2 * x + kw - 1;
                if (zx < 0 || zx >= GI) continue;
                mx = fmaxf(mx, mi[((b * GI + zd) * GI + zh) * GI + zx]);
            }
        }
    }
    mo[v] = mx;
}

// masked global max pool over 24^3 voxels, 64 channels; grid = 2 blocks (batch)
__global__ __launch_bounds__(256) void pool_k(const float* __restrict__ h5,
                                              const float* __restrict__ m3,
                                              float* __restrict__ pooled)
{
    int b = blockIdx.x;
    int c = threadIdx.x & 63;
    int s = threadIdx.x >> 6;  // 4 voxel slices
    float mx = -3.0e38f;
    for (int v = s; v < 13824; v += 4) {
        int gv = b * 13824 + v;
        if (m3[gv] > 0.f) mx = fmaxf(mx, h5[(size_t)gv * 64 + c]);
    }
    __shared__ float red[256];
    red[threadIdx.x] = mx;
    __syncthreads();
    if (s == 0) {
        mx = fmaxf(fmaxf(red[c], red[64 + c]), fmaxf(red[128 + c], red[192 + c]));
        pooled[b * 64 + c] = mx;
    }
}

// head: out = relu(adanorm(pooled @ wh + bh, gh)); 1 block, 128 threads (wave per batch)
__global__ __launch_bounds__(128) void head_k(const float* __restrict__ pooled,
                                              const float* __restrict__ wh,
                                              const float* __restrict__ bh,
                                              const float* __restrict__ gh,
                                              float* __restrict__ out)
{
    int t = threadIdx.x;
    int b = t >> 6;
    int f = t & 63;
    float acc = bh[f];
    for (int k = 0; k < 64; ++k) acc += pooled[b * 64 + k] * wh[k * 64 + f];
    float mean = wave_sum64(acc) * (1.f / 64.f);
    float dd = acc - mean;
    float var = wave_sum64(dd * dd) * (1.f / 64.f) + NEPS;
    float xn = dd * rsqrtf(var);
    float val = gh[f] * (1.f - K_ADA * xn) * xn;
    out[t] = fmaxf(val, 0.f);
}

extern "C" void kernel_launch(void* const* d_in, const int* in_sizes, int n_in,
                              void* d_out, int out_size, void* d_ws, size_t ws_size,
                              hipStream_t stream)
{
    const float* x  = (const float*)d_in[0];
    const float* m1 = (const float*)d_in[1];
    const float* w1 = (const float*)d_in[2];
    const float* b1 = (const float*)d_in[3];
    const float* g1 = (const float*)d_in[4];
    const float* w2 = (const float*)d_in[5];
    const float* b2 = (const float*)d_in[6];
    const float* g2 = (const float*)d_in[7];
    const float* w3 = (const float*)d_in[8];
    const float* b3 = (const float*)d_in[9];
    const float* g3 = (const float*)d_in[10];
    const float* w4 = (const float*)d_in[11];
    const float* b4 = (const float*)d_in[12];
    const float* g4 = (const float*)d_in[13];
    const float* w5 = (const float*)d_in[14];
    const float* b5 = (const float*)d_in[15];
    const float* g5 = (const float*)d_in[16];
    const float* wh = (const float*)d_in[17];
    const float* bh = (const float*)d_in[18];
    const float* gh = (const float*)d_in[19];
    float* out = (float*)d_out;

    float* ws = (float*)d_ws;
    float* h1 = ws;                    // 2*96^3*16 = 28,311,552
    float* h2 = h1 + 28311552;         // 2*48^3*32 =  7,077,888
    float* h3 = h2 + 7077888;          //              7,077,888
    float* h4 = h3 + 7077888;          // 2*24^3*64 =  1,769,472
    float* h5 = h4 + 1769472;          //              1,769,472
    float* m2 = h5 + 1769472;          //    221,184
    float* m3 = m2 + 221184;           //     27,648
    float* pooled = m3 + 27648;        //        128

    // masks
    dmask_k<48, 96><<<(221184 + 255) / 256, 256, 0, stream>>>(m1, m2);
    dmask_k<24, 48><<<(27648 + 255) / 256, 256, 0, stream>>>(m2, m3);

    // layer 1: 96^3, 1->16, s=1, fused norm
    conv_k<96, 96, 1, 16, 16, 1><<<1769472 / 256, 256, 0, stream>>>(x, m1, m1, w1, b1, g1, h1);
    // layer 2: 48^3, 16->32, s=2, fused norm
    conv_k<48, 96, 16, 32, 32, 2><<<221184 / 256, 256, 0, stream>>>(h1, m1, m2, w2, b2, g2, h2);
    // layer 3: 48^3, 32->32, s=1, fused norm
    conv_k<48, 48, 32, 32, 32, 1><<<221184 / 256, 256, 0, stream>>>(h2, m2, m2, w3, b3, g3, h3);
    // layer 4: 24^3, 32->64, s=2, CPT=16 (4 groups), separate norm
    conv_k<24, 48, 32, 64, 16, 2><<<110592 / 256, 256, 0, stream>>>(h3, m2, m3, w4, b4, g4, h4);
    norm64_k<<<1769472 / 256, 256, 0, stream>>>(h4, g4, 1769472);
    // layer 5: 24^3, 64->64, s=1, CPT=16, separate norm
    conv_k<24, 24, 64, 64, 16, 1><<<110592 / 256, 256, 0, stream>>>(h4, m3, m3, w5, b5, g5, h5);
    norm64_k<<<1769472 / 256, 256, 0, stream>>>(h5, g5, 1769472);

    // pool + head
    pool_k<<<2, 256, 0, stream>>>(h5, m3, pooled);
    head_k<<<1, 128, 0, stream>>>(pooled, wh, bh, gh, out);
}

// Round 2
// 1606.217 us; speedup vs baseline: 1.9353x; 1.9353x over previous
//
#include <hip/hip_runtime.h>
#include <math.h>

#define K_ADA 0.1f
#define NEPS 1e-5f

__device__ __forceinline__ float wave_sum64(float v) {
#pragma unroll
    for (int m = 1; m < 64; m <<= 1) v += __shfl_xor(v, m, 64);
    return v;
}

// Generic fused sparse conv3d (k=3, pad=1) + optional AdaNorm+ReLU when CPT==COUT.
// Thread t handles voxel v = t/NG, cout range [g*CPT, (g+1)*CPT) with g = t%NG.
template <int GOUT, int GIN, int CIN, int COUT, int CPT, int STRIDE>
__global__ __launch_bounds__(256) void conv_k(
    const float* __restrict__ hin, const float* __restrict__ m_in,
    const float* __restrict__ m_out, const float* __restrict__ w,
    const float* __restrict__ bias, const float* __restrict__ gain,
    float* __restrict__ hout)
{
    constexpr int NG = COUT / CPT;
    constexpr int NVOX = 2 * GOUT * GOUT * GOUT;
    int t = blockIdx.x * 256 + threadIdx.x;
    if (t >= NVOX * NG) return;
    int g = t % NG;
    int v = t / NG;
    int b = v / (GOUT * GOUT * GOUT);
    int r = v % (GOUT * GOUT * GOUT);
    int d = r / (GOUT * GOUT);
    int hh = (r / GOUT) % GOUT;
    int x = r % GOUT;

    float* outp = hout + (size_t)v * COUT + g * CPT;
    if (m_out[v] == 0.f) {
#pragma unroll
        for (int i = 0; i < CPT / 4; ++i)
            reinterpret_cast<float4*>(outp)[i] = make_float4(0.f, 0.f, 0.f, 0.f);
        return;
    }

    float acc[CPT];
#pragma unroll
    for (int i = 0; i < CPT; ++i) acc[i] = bias[g * CPT + i];

    for (int kd = 0; kd < 3; ++kd) {
        int zd = d * STRIDE + kd - 1;
        if (zd < 0 || zd >= GIN) continue;
        for (int kh = 0; kh < 3; ++kh) {
            int zh = hh * STRIDE + kh - 1;
            if (zh < 0 || zh >= GIN) continue;
            for (int kw = 0; kw < 3; ++kw) {
                int zx = x * STRIDE + kw - 1;
                if (zx < 0 || zx >= GIN) continue;
                int nv = ((b * GIN + zd) * GIN + zh) * GIN + zx;
                if (m_in[nv] == 0.f) continue;  // zero input voxel: exact skip
                const float* ip = hin + (size_t)nv * CIN;
                const float* wp = w + ((kd * 3 + kh) * 3 + kw) * (CIN * COUT) + g * CPT;
                if constexpr (CIN == 1) {
                    float iv = ip[0];
#pragma unroll
                    for (int c4 = 0; c4 < CPT / 4; ++c4) {
                        float4 wv = *reinterpret_cast<const float4*>(wp + c4 * 4);
                        acc[c4 * 4 + 0] += iv * wv.x;
                        acc[c4 * 4 + 1] += iv * wv.y;
                        acc[c4 * 4 + 2] += iv * wv.z;
                        acc[c4 * 4 + 3] += iv * wv.w;
                    }
                } else {
#pragma unroll
                    for (int ci4 = 0; ci4 < CIN / 4; ++ci4) {
                        float4 iv = reinterpret_cast<const float4*>(ip)[ci4];
                        float ivs[4] = {iv.x, iv.y, iv.z, iv.w};
#pragma unroll
                        for (int j = 0; j < 4; ++j) {
                            const float* wr = wp + (ci4 * 4 + j) * COUT;
#pragma unroll
                            for (int c4 = 0; c4 < CPT / 4; ++c4) {
                                float4 wv = *reinterpret_cast<const float4*>(wr + c4 * 4);
                                acc[c4 * 4 + 0] += ivs[j] * wv.x;
                                acc[c4 * 4 + 1] += ivs[j] * wv.y;
                                acc[c4 * 4 + 2] += ivs[j] * wv.z;
                                acc[c4 * 4 + 3] += ivs[j] * wv.w;
                            }
                        }
                    }
                }
            }
        }
    }

    if constexpr (CPT == COUT) {  // fused AdaNorm + ReLU (one thread owns the voxel)
        float mean = 0.f;
#pragma unroll
        for (int i = 0; i < COUT; ++i) mean += acc[i];
        mean *= (1.f / COUT);
        float var = 0.f;
#pragma unroll
        for (int i = 0; i < COUT; ++i) { float dd = acc[i] - mean; var += dd * dd; }
        var = var * (1.f / COUT) + NEPS;
        float rs = rsqrtf(var);
#pragma unroll
        for (int i = 0; i < COUT; ++i) {
            float xn = (acc[i] - mean) * rs;
            float val = gain[i] * (1.f - K_ADA * xn) * xn;
            acc[i] = fmaxf(val, 0.f);
        }
    }
#pragma unroll
    for (int c4 = 0; c4 < CPT / 4; ++c4)
        reinterpret_cast<float4*>(outp)[c4] =
            make_float4(acc[c4 * 4], acc[c4 * 4 + 1], acc[c4 * 4 + 2], acc[c4 * 4 + 3]);
}

// AdaNorm+ReLU over 64 channels, in-place; one wave == one voxel (lane == channel).
__global__ __launch_bounds__(256) void norm64_k(float* __restrict__ h,
                                                const float* __restrict__ gain, int n)
{
    int t = blockIdx.x * 256 + threadIdx.x;
    if (t >= n) return;
    float val = h[t];
    int c = t & 63;
    float mean = wave_sum64(val) * (1.f / 64.f);
    float dd = val - mean;
    float var = wave_sum64(dd * dd) * (1.f / 64.f) + NEPS;
    float xn = dd * rsqrtf(var);
    float o = gain[c] * (1.f - K_ADA * xn) * xn;
    h[t] = fmaxf(o, 0.f);
}

// downsample mask: max over 3^3 window, stride 2, pad 1
template <int GO, int GI>
__global__ __launch_bounds__(256) void dmask_k(const float* __restrict__ mi,
                                               float* __restrict__ mo)
{
    constexpr int N = 2 * GO * GO * GO;
    int v = blockIdx.x * 256 + threadIdx.x;
    if (v >= N) return;
    int b = v / (GO * GO * GO);
    int r = v % (GO * GO * GO);
    int d = r / (GO * GO), h = (r / GO) % GO, x = r % GO;
    float mx = 0.f;
    for (int kd = 0; kd < 3; ++kd) {
        int zd = 2 * d + kd - 1;
        if (zd < 0 || zd >= GI) continue;
        for (int kh = 0; kh < 3; ++kh) {
            int zh = 2 * h + kh - 1;
            if (zh < 0 || zh >= GI) continue;
            for (int kw = 0; kw < 3; ++kw) {
                int zx = 2 * x + kw - 1;
                if (zx < 0 || zx >= GI) continue;
                mx = fmaxf(mx, mi[((b * GI + zd) * GI + zh) * GI + zx]);
            }
        }
    }
    mo[v] = mx;
}

// ---- Global max pool, stage 1 ----
// h5 is post-ReLU (>=0) and zeroed at inactive voxels, and m3 has active voxels in
// every batch, so masked-max == plain max over all voxels. Pure coalesced reads.
// Grid: 2 batches * 54 chunks (256 voxels each). Block 256 = 64 ch * 4 slices.
__global__ __launch_bounds__(256) void pool1_k(const float* __restrict__ h5,
                                               float* __restrict__ partials)
{
    int chunk = blockIdx.x % 54;
    int b = blockIdx.x / 54;
    int c = threadIdx.x & 63;
    int s = threadIdx.x >> 6;
    const float* base = h5 + ((size_t)b * 13824 + chunk * 256) * 64;
    float mx = 0.f;
#pragma unroll 4
    for (int v = s; v < 256; v += 4) mx = fmaxf(mx, base[v * 64 + c]);
    __shared__ float red[256];
    red[threadIdx.x] = mx;
    __syncthreads();
    if (s == 0)
        partials[blockIdx.x * 64 + c] =
            fmaxf(fmaxf(red[c], red[64 + c]), fmaxf(red[128 + c], red[192 + c]));
}

// ---- stage 2 + head fused: reduce 54 partials/batch, then GEMV + AdaNorm + ReLU ----
__global__ __launch_bounds__(128) void pool2_head_k(const float* __restrict__ partials,
                                                    const float* __restrict__ wh,
                                                    const float* __restrict__ bh,
                                                    const float* __restrict__ gh,
                                                    float* __restrict__ out)
{
    __shared__ float pooled[2][64];
    int t = threadIdx.x;
    int b = t >> 6;
    int f = t & 63;
    float mx = 0.f;
    for (int p = 0; p < 54; ++p) mx = fmaxf(mx, partials[(b * 54 + p) * 64 + f]);
    pooled[b][f] = mx;
    __syncthreads();
    float acc = bh[f];
#pragma unroll
    for (int k = 0; k < 64; ++k) acc += pooled[b][k] * wh[k * 64 + f];
    float mean = wave_sum64(acc) * (1.f / 64.f);
    float dd = acc - mean;
    float var = wave_sum64(dd * dd) * (1.f / 64.f) + NEPS;
    float xn = dd * rsqrtf(var);
    float val = gh[f] * (1.f - K_ADA * xn) * xn;
    out[t] = fmaxf(val, 0.f);
}

extern "C" void kernel_launch(void* const* d_in, const int* in_sizes, int n_in,
                              void* d_out, int out_size, void* d_ws, size_t ws_size,
                              hipStream_t stream)
{
    const float* x  = (const float*)d_in[0];
    const float* m1 = (const float*)d_in[1];
    const float* w1 = (const float*)d_in[2];
    const float* b1 = (const float*)d_in[3];
    const float* g1 = (const float*)d_in[4];
    const float* w2 = (const float*)d_in[5];
    const float* b2 = (const float*)d_in[6];
    const float* g2 = (const float*)d_in[7];
    const float* w3 = (const float*)d_in[8];
    const float* b3 = (const float*)d_in[9];
    const float* g3 = (const float*)d_in[10];
    const float* w4 = (const float*)d_in[11];
    const float* b4 = (const float*)d_in[12];
    const float* g4 = (const float*)d_in[13];
    const float* w5 = (const float*)d_in[14];
    const float* b5 = (const float*)d_in[15];
    const float* g5 = (const float*)d_in[16];
    const float* wh = (const float*)d_in[17];
    const float* bh = (const float*)d_in[18];
    const float* gh = (const float*)d_in[19];
    float* out = (float*)d_out;

    float* ws = (float*)d_ws;
    float* h1 = ws;                    // 2*96^3*16 = 28,311,552
    float* h2 = h1 + 28311552;         // 2*48^3*32 =  7,077,888
    float* h3 = h2 + 7077888;          //              7,077,888
    float* h4 = h3 + 7077888;          // 2*24^3*64 =  1,769,472
    float* h5 = h4 + 1769472;          //              1,769,472
    float* m2 = h5 + 1769472;          //    221,184
    float* m3 = m2 + 221184;           //     27,648
    float* partials = m3 + 27648;      //  108*64 = 6912

    // masks
    dmask_k<48, 96><<<(221184 + 255) / 256, 256, 0, stream>>>(m1, m2);
    dmask_k<24, 48><<<(27648 + 255) / 256, 256, 0, stream>>>(m2, m3);

    // layer 1: 96^3, 1->16, s=1, fused norm
    conv_k<96, 96, 1, 16, 16, 1><<<1769472 / 256, 256, 0, stream>>>(x, m1, m1, w1, b1, g1, h1);
    // layer 2: 48^3, 16->32, s=2, fused norm
    conv_k<48, 96, 16, 32, 32, 2><<<221184 / 256, 256, 0, stream>>>(h1, m1, m2, w2, b2, g2, h2);
    // layer 3: 48^3, 32->32, s=1, fused norm
    conv_k<48, 48, 32, 32, 32, 1><<<221184 / 256, 256, 0, stream>>>(h2, m2, m2, w3, b3, g3, h3);
    // layer 4: 24^3, 32->64, s=2, CPT=16 (4 groups), separate norm
    conv_k<24, 48, 32, 64, 16, 2><<<110592 / 256, 256, 0, stream>>>(h3, m2, m3, w4, b4, g4, h4);
    norm64_k<<<1769472 / 256, 256, 0, stream>>>(h4, g4, 1769472);
    // layer 5: 24^3, 64->64, s=1, CPT=16, separate norm
    conv_k<24, 24, 64, 64, 16, 1><<<110592 / 256, 256, 0, stream>>>(h4, m3, m3, w5, b5, g5, h5);
    norm64_k<<<1769472 / 256, 256, 0, stream>>>(h5, g5, 1769472);

    // pool (2-stage) + head
    pool1_k<<<108, 256, 0, stream>>>(h5, partials);
    pool2_head_k<<<1, 128, 0, stream>>>(partials, wh, bh, gh, out);
}

// Round 3
// 455.318 us; speedup vs baseline: 6.8271x; 3.5277x over previous
//
#include <hip/hip_runtime.h>
#include <math.h>

#define K_ADA 0.1f
#define NEPS 1e-5f

typedef __attribute__((ext_vector_type(8))) short short8;
typedef __attribute__((ext_vector_type(4))) float f32x4;
typedef unsigned short ushort_t;

__device__ __forceinline__ ushort_t f2b(float f) {
    union { float f; unsigned u; } v; v.f = f;
    unsigned r = (v.u + 0x7fffu + ((v.u >> 16) & 1u)) >> 16;
    return (ushort_t)r;
}
__device__ __forceinline__ float b2f(ushort_t h) {
    union { unsigned u; float f; } v; v.u = ((unsigned)h) << 16;
    return v.f;
}

__device__ __forceinline__ float wave_sum64(float v) {
#pragma unroll
    for (int m = 1; m < 64; m <<= 1) v += __shfl_xor(v, m, 64);
    return v;
}
__device__ __forceinline__ float wave_sum32(float v) {
#pragma unroll
    for (int m = 1; m < 32; m <<= 1) v += __shfl_xor(v, m, 32);
    return v;
}

// ---- pack weights [3,3,3,CIN,COUT] fp32 -> MFMA B-fragment-ordered bf16 ----
// dst[(((tap*(COUT/16)+ct)*(CIN/32)+kh)*64+lane)*8+jj] = W[tap][kh*32+(lane>>4)*8+jj][ct*16+(lane&15)]
template <int CIN, int COUT>
__global__ __launch_bounds__(256) void pack_w_k(const float* __restrict__ w,
                                                ushort_t* __restrict__ wp)
{
    constexpr int TOTAL = 27 * CIN * COUT;
    int t = blockIdx.x * 256 + threadIdx.x;
    if (t >= TOTAL) return;
    constexpr int NKH = CIN / 32;
    constexpr int NCT = COUT / 16;
    int jj = t & 7;
    int lane = (t >> 3) & 63;
    int rest = t >> 9;              // (tap*NCT + ct)*NKH + kh
    int kh = rest % NKH;
    int rest2 = rest / NKH;
    int ct = rest2 % NCT;
    int tap = rest2 / NCT;
    int cin = kh * 32 + (lane >> 4) * 8 + jj;
    int cout = ct * 16 + (lane & 15);
    wp[t] = f2b(w[(tap * CIN + cin) * COUT + cout]);
}

// ---- layer 1: 96^3, 1->16, s=1, scalar conv + fused AdaNorm+ReLU -> bf16 ----
// Writes ONLY active voxels (inactive h1b entries are never read by layer 2).
__global__ __launch_bounds__(256) void conv1_k(const float* __restrict__ x,
                                               const float* __restrict__ m1,
                                               const float* __restrict__ w,
                                               const float* __restrict__ bias,
                                               const float* __restrict__ gain,
                                               ushort_t* __restrict__ h1b)
{
    constexpr int G = 96;
    int v = blockIdx.x * 256 + threadIdx.x;
    if (v >= 2 * G * G * G) return;
    if (m1[v] == 0.f) return;
    int b = v / (G * G * G);
    int r = v % (G * G * G);
    int d = r / (G * G), hh = (r / G) % G, xx = r % G;

    float acc[16];
#pragma unroll
    for (int i = 0; i < 16; ++i) acc[i] = bias[i];

    for (int kd = 0; kd < 3; ++kd) {
        int zd = d + kd - 1; if ((unsigned)zd >= G) continue;
        for (int kh = 0; kh < 3; ++kh) {
            int zh = hh + kh - 1; if ((unsigned)zh >= G) continue;
            for (int kw = 0; kw < 3; ++kw) {
                int zx = xx + kw - 1; if ((unsigned)zx >= G) continue;
                int nv = ((b * G + zd) * G + zh) * G + zx;
                if (m1[nv] == 0.f) continue;
                float iv = x[nv];
                const float* wp = w + ((kd * 3 + kh) * 3 + kw) * 16;
#pragma unroll
                for (int c4 = 0; c4 < 4; ++c4) {
                    float4 wv = *reinterpret_cast<const float4*>(wp + c4 * 4);
                    acc[c4 * 4 + 0] += iv * wv.x;
                    acc[c4 * 4 + 1] += iv * wv.y;
                    acc[c4 * 4 + 2] += iv * wv.z;
                    acc[c4 * 4 + 3] += iv * wv.w;
                }
            }
        }
    }
    float mean = 0.f;
#pragma unroll
    for (int i = 0; i < 16; ++i) mean += acc[i];
    mean *= (1.f / 16.f);
    float var = 0.f;
#pragma unroll
    for (int i = 0; i < 16; ++i) { float dd = acc[i] - mean; var += dd * dd; }
    float rs = rsqrtf(var * (1.f / 16.f) + NEPS);
    ushort_t ob[16];
#pragma unroll
    for (int i = 0; i < 16; ++i) {
        float xn = (acc[i] - mean) * rs;
        ob[i] = f2b(fmaxf(gain[i] * (1.f - K_ADA * xn) * xn, 0.f));
    }
    short8* op = reinterpret_cast<short8*>(h1b + (size_t)v * 16);
    op[0] = *reinterpret_cast<short8*>(ob);
    op[1] = *reinterpret_cast<short8*>(ob + 8);
}

// ---- layer 2: 48^3, 16->32, s=2, scalar conv (bf16 in) + fused norm -> bf16 dense ----
__global__ __launch_bounds__(256) void conv2_k(const ushort_t* __restrict__ h1b,
                                               const float* __restrict__ m1,
                                               const float* __restrict__ m2,
                                               const float* __restrict__ w,
                                               const float* __restrict__ bias,
                                               const float* __restrict__ gain,
                                               ushort_t* __restrict__ h2b)
{
    constexpr int G = 48, GI = 96;
    int v = blockIdx.x * 256 + threadIdx.x;
    if (v >= 2 * G * G * G) return;
    short8* op = reinterpret_cast<short8*>(h2b + (size_t)v * 32);
    if (m2[v] == 0.f) {
        short8 z = {0, 0, 0, 0, 0, 0, 0, 0};
        op[0] = z; op[1] = z; op[2] = z; op[3] = z;
        return;
    }
    int b = v / (G * G * G);
    int r = v % (G * G * G);
    int d = r / (G * G), hh = (r / G) % G, xx = r % G;

    float acc[32];
#pragma unroll
    for (int i = 0; i < 32; ++i) acc[i] = bias[i];

    for (int kd = 0; kd < 3; ++kd) {
        int zd = 2 * d + kd - 1; if ((unsigned)zd >= GI) continue;
        for (int kh = 0; kh < 3; ++kh) {
            int zh = 2 * hh + kh - 1; if ((unsigned)zh >= GI) continue;
            for (int kw = 0; kw < 3; ++kw) {
                int zx = 2 * xx + kw - 1; if ((unsigned)zx >= GI) continue;
                int nv = ((b * GI + zd) * GI + zh) * GI + zx;
                if (m1[nv] == 0.f) continue;
                const ushort_t* ip = h1b + (size_t)nv * 16;
                const float* wp = w + ((kd * 3 + kh) * 3 + kw) * (16 * 32);
#pragma unroll
                for (int ci = 0; ci < 16; ++ci) {
                    float iv = b2f(ip[ci]);
                    const float* wr = wp + ci * 32;
#pragma unroll
                    for (int c4 = 0; c4 < 8; ++c4) {
                        float4 wv = *reinterpret_cast<const float4*>(wr + c4 * 4);
                        acc[c4 * 4 + 0] += iv * wv.x;
                        acc[c4 * 4 + 1] += iv * wv.y;
                        acc[c4 * 4 + 2] += iv * wv.z;
                        acc[c4 * 4 + 3] += iv * wv.w;
                    }
                }
            }
        }
    }
    float mean = 0.f;
#pragma unroll
    for (int i = 0; i < 32; ++i) mean += acc[i];
    mean *= (1.f / 32.f);
    float var = 0.f;
#pragma unroll
    for (int i = 0; i < 32; ++i) { float dd = acc[i] - mean; var += dd * dd; }
    float rs = rsqrtf(var * (1.f / 32.f) + NEPS);
    ushort_t ob[32];
#pragma unroll
    for (int i = 0; i < 32; ++i) {
        float xn = (acc[i] - mean) * rs;
        ob[i] = f2b(fmaxf(gain[i] * (1.f - K_ADA * xn) * xn, 0.f));
    }
#pragma unroll
    for (int i = 0; i < 4; ++i) op[i] = reinterpret_cast<short8*>(ob)[i];
}

// ---- MFMA implicit-GEMM conv: one wave per (16-voxel tile, 16-cout tile) ----
// A = activations [voxel][cin] bf16 (zeros at inactive => exact dense conv)
// B = packed weights (frag order), C = fp32 conv out (+bias), dense.
template <int G_OUT, int G_IN, int CIN, int COUT, int STRIDE>
__global__ __launch_bounds__(256) void conv_mfma_k(const ushort_t* __restrict__ Ab,
                                                   const ushort_t* __restrict__ Wp,
                                                   const float* __restrict__ bias,
                                                   float* __restrict__ Co)
{
    constexpr int G3 = G_OUT * G_OUT * G_OUT;
    constexpr int NCT = COUT / 16;
    constexpr int NKH = CIN / 32;
    int wave = (blockIdx.x * 256 + threadIdx.x) >> 6;
    int lane = threadIdx.x & 63;
    int ct = wave % NCT;
    int tile = wave / NCT;
    int vb = tile * 16;
    int m = lane & 15;
    int q = lane >> 4;

    int vm = vb + m;
    int b = vm / G3;
    int rr = vm % G3;
    int dm = rr / (G_OUT * G_OUT);
    int hm = (rr / G_OUT) % G_OUT;
    int xm = rr % G_OUT;

    f32x4 acc = {0.f, 0.f, 0.f, 0.f};
    const short8 z8 = {0, 0, 0, 0, 0, 0, 0, 0};

    for (int kd = 0; kd < 3; ++kd) {
        int id = dm * STRIDE + kd - 1;
        for (int kh = 0; kh < 3; ++kh) {
            int ih = hm * STRIDE + kh - 1;
#pragma unroll
            for (int kw = 0; kw < 3; ++kw) {
                int ix = xm * STRIDE + kw - 1;
                bool ok = ((unsigned)id < (unsigned)G_IN) &&
                          ((unsigned)ih < (unsigned)G_IN) &&
                          ((unsigned)ix < (unsigned)G_IN);
                size_t nv = (((size_t)b * G_IN + id) * G_IN + ih) * G_IN + ix;
                const ushort_t* arow = Ab + nv * CIN + q * 8;
                int tap = (kd * 3 + kh) * 3 + kw;
#pragma unroll
                for (int k2 = 0; k2 < NKH; ++k2) {
                    short8 a = ok ? *reinterpret_cast<const short8*>(arow + k2 * 32) : z8;
                    short8 bf = *reinterpret_cast<const short8*>(
                        Wp + (((size_t)(tap * NCT + ct) * NKH + k2) * 64 + lane) * 8);
                    acc = __builtin_amdgcn_mfma_f32_16x16x32_bf16(a, bf, acc, 0, 0, 0);
                }
            }
        }
    }
    int n = ct * 16 + m;
    float bn = bias[n];
#pragma unroll
    for (int i = 0; i < 4; ++i)
        Co[(size_t)(vb + q * 4 + i) * COUT + n] = acc[i] + bn;
}

// ---- AdaNorm+ReLU over 32 channels (2 voxels / wave), mask-aware, fp32->bf16 ----
__global__ __launch_bounds__(256) void norm32_b_k(const float* __restrict__ c,
                                                  const float* __restrict__ mask,
                                                  const float* __restrict__ gain,
                                                  ushort_t* __restrict__ outb, int n)
{
    int t = blockIdx.x * 256 + threadIdx.x;
    if (t >= n) return;
    int v = t >> 5;
    int ch = t & 31;
    float val = c[t];
    float mean = wave_sum32(val) * (1.f / 32.f);
    float dd = val - mean;
    float var = wave_sum32(dd * dd) * (1.f / 32.f) + NEPS;
    float xn = dd * rsqrtf(var);
    float o = fmaxf(gain[ch] * (1.f - K_ADA * xn) * xn, 0.f);
    outb[t] = (mask[v] != 0.f) ? f2b(o) : (ushort_t)0;
}

// ---- AdaNorm+ReLU over 64 channels, mask-aware, fp32->bf16 ----
__global__ __launch_bounds__(256) void norm64_b_k(const float* __restrict__ c,
                                                  const float* __restrict__ mask,
                                                  const float* __restrict__ gain,
                                                  ushort_t* __restrict__ outb, int n)
{
    int t = blockIdx.x * 256 + threadIdx.x;
    if (t >= n) return;
    int v = t >> 6;
    int ch = t & 63;
    float val = c[t];
    float mean = wave_sum64(val) * (1.f / 64.f);
    float dd = val - mean;
    float var = wave_sum64(dd * dd) * (1.f / 64.f) + NEPS;
    float xn = dd * rsqrtf(var);
    float o = fmaxf(gain[ch] * (1.f - K_ADA * xn) * xn, 0.f);
    outb[t] = (mask[v] != 0.f) ? f2b(o) : (ushort_t)0;
}

// ---- AdaNorm+ReLU over 64 channels, mask-aware, fp32 in-place (layer 5) ----
__global__ __launch_bounds__(256) void norm64_f_k(float* __restrict__ c,
                                                  const float* __restrict__ mask,
                                                  const float* __restrict__ gain, int n)
{
    int t = blockIdx.x * 256 + threadIdx.x;
    if (t >= n) return;
    int v = t >> 6;
    int ch = t & 63;
    float val = c[t];
    float mean = wave_sum64(val) * (1.f / 64.f);
    float dd = val - mean;
    float var = wave_sum64(dd * dd) * (1.f / 64.f) + NEPS;
    float xn = dd * rsqrtf(var);
    float o = fmaxf(gain[ch] * (1.f - K_ADA * xn) * xn, 0.f);
    c[t] = (mask[v] != 0.f) ? o : 0.f;
}

// downsample mask: max over 3^3 window, stride 2, pad 1
template <int GO, int GI>
__global__ __launch_bounds__(256) void dmask_k(const float* __restrict__ mi,
                                               float* __restrict__ mo)
{
    constexpr int N = 2 * GO * GO * GO;
    int v = blockIdx.x * 256 + threadIdx.x;
    if (v >= N) return;
    int b = v / (GO * GO * GO);
    int r = v % (GO * GO * GO);
    int d = r / (GO * GO), h = (r / GO) % GO, x = r % GO;
    float mx = 0.f;
    for (int kd = 0; kd < 3; ++kd) {
        int zd = 2 * d + kd - 1; if ((unsigned)zd >= GI) continue;
        for (int kh = 0; kh < 3; ++kh) {
            int zh = 2 * h + kh - 1; if ((unsigned)zh >= GI) continue;
            for (int kw = 0; kw < 3; ++kw) {
                int zx = 2 * x + kw - 1; if ((unsigned)zx >= GI) continue;
                mx = fmaxf(mx, mi[((b * GI + zd) * GI + zh) * GI + zx]);
            }
        }
    }
    mo[v] = mx;
}

// ---- Global max pool stage 1 (h5 is >=0 with zeros at inactive -> plain max) ----
__global__ __launch_bounds__(256) void pool1_k(const float* __restrict__ h5,
                                               float* __restrict__ partials)
{
    int chunk = blockIdx.x % 54;
    int b = blockIdx.x / 54;
    int c = threadIdx.x & 63;
    int s = threadIdx.x >> 6;
    const float* base = h5 + ((size_t)b * 13824 + chunk * 256) * 64;
    float mx = 0.f;
#pragma unroll 4
    for (int v = s; v < 256; v += 4) mx = fmaxf(mx, base[v * 64 + c]);
    __shared__ float red[256];
    red[threadIdx.x] = mx;
    __syncthreads();
    if (s == 0)
        partials[blockIdx.x * 64 + c] =
            fmaxf(fmaxf(red[c], red[64 + c]), fmaxf(red[128 + c], red[192 + c]));
}

// ---- stage 2 + head ----
__global__ __launch_bounds__(128) void pool2_head_k(const float* __restrict__ partials,
                                                    const float* __restrict__ wh,
                                                    const float* __restrict__ bh,
                                                    const float* __restrict__ gh,
                                                    float* __restrict__ out)
{
    __shared__ float pooled[2][64];
    int t = threadIdx.x;
    int b = t >> 6;
    int f = t & 63;
    float mx = 0.f;
    for (int p = 0; p < 54; ++p) mx = fmaxf(mx, partials[(b * 54 + p) * 64 + f]);
    pooled[b][f] = mx;
    __syncthreads();
    float acc = bh[f];
#pragma unroll
    for (int k = 0; k < 64; ++k) acc += pooled[b][k] * wh[k * 64 + f];
    float mean = wave_sum64(acc) * (1.f / 64.f);
    float dd = acc - mean;
    float var = wave_sum64(dd * dd) * (1.f / 64.f) + NEPS;
    float xn = dd * rsqrtf(var);
    float val = gh[f] * (1.f - K_ADA * xn) * xn;
    out[t] = fmaxf(val, 0.f);
}

extern "C" void kernel_launch(void* const* d_in, const int* in_sizes, int n_in,
                              void* d_out, int out_size, void* d_ws, size_t ws_size,
                              hipStream_t stream)
{
    const float* x  = (const float*)d_in[0];
    const float* m1 = (const float*)d_in[1];
    const float* w1 = (const float*)d_in[2];
    const float* b1 = (const float*)d_in[3];
    const float* g1 = (const float*)d_in[4];
    const float* w2 = (const float*)d_in[5];
    const float* b2 = (const float*)d_in[6];
    const float* g2 = (const float*)d_in[7];
    const float* w3 = (const float*)d_in[8];
    const float* b3 = (const float*)d_in[9];
    const float* g3 = (const float*)d_in[10];
    const float* w4 = (const float*)d_in[11];
    const float* b4 = (const float*)d_in[12];
    const float* g4 = (const float*)d_in[13];
    const float* w5 = (const float*)d_in[14];
    const float* b5 = (const float*)d_in[15];
    const float* g5 = (const float*)d_in[16];
    const float* wh = (const float*)d_in[17];
    const float* bh = (const float*)d_in[18];
    const float* gh = (const float*)d_in[19];
    float* out = (float*)d_out;

    // workspace layout (all 16B-aligned; counted in float units)
    float* ws = (float*)d_ws;
    ushort_t* h1b = (ushort_t*)ws;                        // 28,311,552 bf16 = 14,155,776 f
    ushort_t* h2b = (ushort_t*)(ws + 14155776);           //  7,077,888 bf16 =  3,538,944 f
    float* c3 = ws + 14155776 + 3538944;                  //  7,077,888 f
    ushort_t* h3b = (ushort_t*)(c3 + 7077888);            //  7,077,888 bf16 =  3,538,944 f
    float* c4 = c3 + 7077888 + 3538944;                   //  1,769,472 f
    ushort_t* h4b = (ushort_t*)(c4 + 1769472);            //  1,769,472 bf16 =    884,736 f
    float* c5 = c4 + 1769472 + 884736;                    //  1,769,472 f (in-place -> h5)
    float* m2 = c5 + 1769472;                             //    221,184 f
    float* m3 = m2 + 221184;                              //     27,648 f
    float* partials = m3 + 27648;                         //      6,912 f
    ushort_t* wp3 = (ushort_t*)(partials + 6912);         //  27,648 bf16 = 13,824 f
    ushort_t* wp4 = (ushort_t*)(partials + 6912 + 13824); //  55,296 bf16 = 27,648 f
    ushort_t* wp5 = (ushort_t*)(partials + 6912 + 13824 + 27648); // 110,592 bf16

    // weight packing (B-fragment order, bf16)
    pack_w_k<32, 32><<<108, 256, 0, stream>>>(w3, wp3);
    pack_w_k<32, 64><<<216, 256, 0, stream>>>(w4, wp4);
    pack_w_k<64, 64><<<432, 256, 0, stream>>>(w5, wp5);

    // masks
    dmask_k<48, 96><<<864, 256, 0, stream>>>(m1, m2);
    dmask_k<24, 48><<<108, 256, 0, stream>>>(m2, m3);

    // layer 1 (scalar sparse, bf16 out, active-only writes)
    conv1_k<<<6912, 256, 0, stream>>>(x, m1, w1, b1, g1, h1b);
    // layer 2 (scalar sparse-gather, bf16 dense out)
    conv2_k<<<864, 256, 0, stream>>>(h1b, m1, m2, w2, b2, g2, h2b);

    // layer 3 (MFMA): 13824 tiles * 2 cout-tiles = 27648 waves -> 6912 blocks
    conv_mfma_k<48, 48, 32, 32, 1><<<6912, 256, 0, stream>>>(h2b, wp3, b3, c3);
    norm32_b_k<<<27648, 256, 0, stream>>>(c3, m2, g3, h3b, 7077888);

    // layer 4 (MFMA): 1728 tiles * 4 cout-tiles = 6912 waves -> 1728 blocks
    conv_mfma_k<24, 48, 32, 64, 2><<<1728, 256, 0, stream>>>(h3b, wp4, b4, c4);
    norm64_b_k<<<6912, 256, 0, stream>>>(c4, m3, g4, h4b, 1769472);

    // layer 5 (MFMA): 6912 waves -> 1728 blocks
    conv_mfma_k<24, 24, 64, 64, 1><<<1728, 256, 0, stream>>>(h4b, wp5, b5, c5);
    norm64_f_k<<<6912, 256, 0, stream>>>(c5, m3, g5, 1769472);

    // pool + head
    pool1_k<<<108, 256, 0, stream>>>(c5, partials);
    pool2_head_k<<<1, 128, 0, stream>>>(partials, wh, bh, gh, out);
}

// Round 4
// 360.217 us; speedup vs baseline: 8.6296x; 1.2640x over previous
//
#include <hip/hip_runtime.h>
#include <math.h>

#define K_ADA 0.1f
#define NEPS 1e-5f

typedef __attribute__((ext_vector_type(8))) short short8;
typedef __attribute__((ext_vector_type(4))) float f32x4;
typedef unsigned short ushort_t;

__device__ __forceinline__ ushort_t f2b(float f) {
    union { float f; unsigned u; } v; v.f = f;
    unsigned r = (v.u + 0x7fffu + ((v.u >> 16) & 1u)) >> 16;
    return (ushort_t)r;
}

__device__ __forceinline__ float wave_sum64(float v) {
#pragma unroll
    for (int m = 1; m < 64; m <<= 1) v += __shfl_xor(v, m, 64);
    return v;
}

// ---- pack weights [3,3,3,CIN,COUT] fp32 -> MFMA B-fragment-ordered bf16 ----
// dst[(((tap*(COUT/16)+ct)*(CIN/32)+kh)*64+lane)*8+jj]
//   = W[tap][kh*32+(lane>>4)*8+jj][ct*16+(lane&15)]
template <int CIN, int COUT>
__global__ __launch_bounds__(256) void pack_w_k(const float* __restrict__ w,
                                                ushort_t* __restrict__ wp)
{
    constexpr int TOTAL = 27 * CIN * COUT;
    int t = blockIdx.x * 256 + threadIdx.x;
    if (t >= TOTAL) return;
    constexpr int NKH = CIN / 32;
    constexpr int NCT = COUT / 16;
    int jj = t & 7;
    int lane = (t >> 3) & 63;
    int rest = t >> 9;              // (tap*NCT + ct)*NKH + kh
    int kh = rest % NKH;
    int rest2 = rest / NKH;
    int ct = rest2 % NCT;
    int tap = rest2 / NCT;
    int cin = kh * 32 + (lane >> 4) * 8 + jj;
    int cout = ct * 16 + (lane & 15);
    wp[t] = f2b(w[(tap * CIN + cin) * COUT + cout]);
}

// ---- pack w2 [27][16][32] -> tap-paired B frags: 14 pairs x 2 ct ----
// dst[((p*2+ct)*64+lane)*8+jj] = W2[2p+(lane>>5)][((lane>>4)&1)*8+jj][ct*16+(lane&15)]
__global__ __launch_bounds__(256) void pack_w2_k(const float* __restrict__ w,
                                                 ushort_t* __restrict__ wp)
{
    constexpr int TOTAL = 14 * 2 * 64 * 8;  // 14336
    int t = blockIdx.x * 256 + threadIdx.x;
    if (t >= TOTAL) return;
    int jj = t & 7;
    int lane = (t >> 3) & 63;
    int rest = t >> 9;              // p*2 + ct
    int ct = rest & 1;
    int p = rest >> 1;
    int tap = 2 * p + (lane >> 5);
    int cin = ((lane >> 4) & 1) * 8 + jj;
    int cout = ct * 16 + (lane & 15);
    wp[t] = (tap < 27) ? f2b(w[(tap * 16 + cin) * 32 + cout]) : (ushort_t)0;
}

// ---- layer 1: 96^3, 1->16, s=1, DENSE conv (x pre-masked) + norm -> bf16 dense ----
__global__ __launch_bounds__(256) void conv1_k(const float* __restrict__ x,
                                               const float* __restrict__ m1,
                                               const float* __restrict__ w,
                                               const float* __restrict__ bias,
                                               const float* __restrict__ gain,
                                               ushort_t* __restrict__ h1b)
{
    constexpr int G = 96;
    int v = blockIdx.x * 256 + threadIdx.x;
    if (v >= 2 * G * G * G) return;
    short8* op = reinterpret_cast<short8*>(h1b + (size_t)v * 16);
    if (m1[v] == 0.f) {
        short8 z = {0, 0, 0, 0, 0, 0, 0, 0};
        op[0] = z; op[1] = z;
        return;
    }
    int b = v / (G * G * G);
    int r = v % (G * G * G);
    int d = r / (G * G), hh = (r / G) % G, xx = r % G;

    float acc[16];
#pragma unroll
    for (int i = 0; i < 16; ++i) acc[i] = bias[i];

    for (int kd = 0; kd < 3; ++kd) {
        int zd = d + kd - 1; if ((unsigned)zd >= G) continue;
        for (int kh = 0; kh < 3; ++kh) {
            int zh = hh + kh - 1; if ((unsigned)zh >= G) continue;
#pragma unroll
            for (int kw = 0; kw < 3; ++kw) {
                int zx = xx + kw - 1; if ((unsigned)zx >= G) continue;
                float iv = x[((b * G + zd) * G + zh) * G + zx];  // exact zeros at inactive
                const float* wp = w + ((kd * 3 + kh) * 3 + kw) * 16;
#pragma unroll
                for (int c4 = 0; c4 < 4; ++c4) {
                    float4 wv = *reinterpret_cast<const float4*>(wp + c4 * 4);
                    acc[c4 * 4 + 0] += iv * wv.x;
                    acc[c4 * 4 + 1] += iv * wv.y;
                    acc[c4 * 4 + 2] += iv * wv.z;
                    acc[c4 * 4 + 3] += iv * wv.w;
                }
            }
        }
    }
    float mean = 0.f;
#pragma unroll
    for (int i = 0; i < 16; ++i) mean += acc[i];
    mean *= (1.f / 16.f);
    float var = 0.f;
#pragma unroll
    for (int i = 0; i < 16; ++i) { float dd = acc[i] - mean; var += dd * dd; }
    float rs = rsqrtf(var * (1.f / 16.f) + NEPS);
    ushort_t ob[16];
#pragma unroll
    for (int i = 0; i < 16; ++i) {
        float xn = (acc[i] - mean) * rs;
        ob[i] = f2b(fmaxf(gain[i] * (1.f - K_ADA * xn) * xn, 0.f));
    }
    op[0] = *reinterpret_cast<short8*>(ob);
    op[1] = *reinterpret_cast<short8*>(ob + 8);
}

// ---- fused 32-channel AdaNorm+ReLU epilogue (wave holds 16 voxels x 32 couts) ----
// acc0 = couts [0,16), acc1 = couts [16,32); C-frag: col n = lane&15, row = q*4+i.
__device__ __forceinline__ void norm32_epilogue(
    f32x4 acc0, f32x4 acc1, int vb, int q, int n,
    const float* __restrict__ bias, const float* __restrict__ gain,
    const float* __restrict__ mask, ushort_t* __restrict__ outb)
{
    float b0 = bias[n], b1 = bias[16 + n];
    float g0 = gain[n], g1 = gain[16 + n];
#pragma unroll
    for (int i = 0; i < 4; ++i) {
        int w = vb + q * 4 + i;
        float x0 = acc0[i] + b0;
        float x1 = acc1[i] + b1;
        float s = x0 + x1;
#pragma unroll
        for (int mk = 1; mk < 16; mk <<= 1) s += __shfl_xor(s, mk, 64);
        float mean = s * (1.f / 32.f);
        float d0 = x0 - mean, d1 = x1 - mean;
        float ss = d0 * d0 + d1 * d1;
#pragma unroll
        for (int mk = 1; mk < 16; mk <<= 1) ss += __shfl_xor(ss, mk, 64);
        float rs = rsqrtf(ss * (1.f / 32.f) + NEPS);
        float mv = mask[w];
        float xn0 = d0 * rs, xn1 = d1 * rs;
        float o0 = fmaxf(g0 * (1.f - K_ADA * xn0) * xn0, 0.f);
        float o1 = fmaxf(g1 * (1.f - K_ADA * xn1) * xn1, 0.f);
        if (mv == 0.f) { o0 = 0.f; o1 = 0.f; }
        outb[(size_t)w * 32 + n]      = f2b(o0);
        outb[(size_t)w * 32 + 16 + n] = f2b(o1);
    }
}

// ---- layer 2 MFMA: 16->32, s=2, K=32 spans a tap PAIR; fused norm -> bf16 ----
__global__ __launch_bounds__(256) void conv2_mfma_k(
    const ushort_t* __restrict__ h1b, const ushort_t* __restrict__ wp2,
    const float* __restrict__ bias, const float* __restrict__ gain,
    const float* __restrict__ m2, ushort_t* __restrict__ h2b)
{
    constexpr int G = 48, GI = 96, G3 = G * G * G;
    int wave = (blockIdx.x * 256 + threadIdx.x) >> 6;
    int lane = threadIdx.x & 63;
    int m = lane & 15, q = lane >> 4;
    int vb = wave * 16;
    int vm = vb + m;
    int b = vm / G3;
    int rr = vm % G3;
    int dm = rr / (G * G), hm = (rr / G) % G, xm = rr % G;
    int tq = q >> 1;   // which tap within pair
    int hq = q & 1;    // which cin half

    f32x4 acc0 = {0.f, 0.f, 0.f, 0.f};
    f32x4 acc1 = {0.f, 0.f, 0.f, 0.f};
    const short8 z8 = {0, 0, 0, 0, 0, 0, 0, 0};
#pragma unroll
    for (int p = 0; p < 14; ++p) {
        int tap = 2 * p + tq;
        int kd = tap / 9, kh = (tap / 3) % 3, kw = tap % 3;
        int id = 2 * dm + kd - 1, ih = 2 * hm + kh - 1, ix = 2 * xm + kw - 1;
        bool ok = (tap < 27) && ((unsigned)id < (unsigned)GI) &&
                  ((unsigned)ih < (unsigned)GI) && ((unsigned)ix < (unsigned)GI);
        size_t nv = (((size_t)b * GI + id) * GI + ih) * GI + ix;
        short8 a = ok ? *reinterpret_cast<const short8*>(h1b + nv * 16 + hq * 8) : z8;
        short8 bv0 = *reinterpret_cast<const short8*>(wp2 + ((size_t)(p * 2 + 0) * 64 + lane) * 8);
        short8 bv1 = *reinterpret_cast<const short8*>(wp2 + ((size_t)(p * 2 + 1) * 64 + lane) * 8);
        acc0 = __builtin_amdgcn_mfma_f32_16x16x32_bf16(a, bv0, acc0, 0, 0, 0);
        acc1 = __builtin_amdgcn_mfma_f32_16x16x32_bf16(a, bv1, acc1, 0, 0, 0);
    }
    norm32_epilogue(acc0, acc1, vb, q, m, bias, gain, m2, h2b);
}

// ---- layer 3 MFMA: 32->32, s=1, one tap per MFMA; fused norm -> bf16 ----
__global__ __launch_bounds__(256) void conv3_mfma_k(
    const ushort_t* __restrict__ h2b, const ushort_t* __restrict__ wp3,
    const float* __restrict__ bias, const float* __restrict__ gain,
    const float* __restrict__ m2, ushort_t* __restrict__ h3b)
{
    constexpr int G = 48, G3 = G * G * G;
    int wave = (blockIdx.x * 256 + threadIdx.x) >> 6;
    int lane = threadIdx.x & 63;
    int m = lane & 15, q = lane >> 4;
    int vb = wave * 16;
    int vm = vb + m;
    int b = vm / G3;
    int rr = vm % G3;
    int dm = rr / (G * G), hm = (rr / G) % G, xm = rr % G;

    f32x4 acc0 = {0.f, 0.f, 0.f, 0.f};
    f32x4 acc1 = {0.f, 0.f, 0.f, 0.f};
    const short8 z8 = {0, 0, 0, 0, 0, 0, 0, 0};
    for (int kd = 0; kd < 3; ++kd) {
        int id = dm + kd - 1;
        for (int kh = 0; kh < 3; ++kh) {
            int ih = hm + kh - 1;
#pragma unroll
            for (int kw = 0; kw < 3; ++kw) {
                int ix = xm + kw - 1;
                bool ok = ((unsigned)id < (unsigned)G) && ((unsigned)ih < (unsigned)G) &&
                          ((unsigned)ix < (unsigned)G);
                size_t nv = (((size_t)b * G + id) * G + ih) * G + ix;
                int tap = (kd * 3 + kh) * 3 + kw;
                short8 a = ok ? *reinterpret_cast<const short8*>(h2b + nv * 32 + q * 8) : z8;
                short8 bv0 = *reinterpret_cast<const short8*>(wp3 + ((size_t)(tap * 2 + 0) * 64 + lane) * 8);
                short8 bv1 = *reinterpret_cast<const short8*>(wp3 + ((size_t)(tap * 2 + 1) * 64 + lane) * 8);
                acc0 = __builtin_amdgcn_mfma_f32_16x16x32_bf16(a, bv0, acc0, 0, 0, 0);
                acc1 = __builtin_amdgcn_mfma_f32_16x16x32_bf16(a, bv1, acc1, 0, 0, 0);
            }
        }
    }
    norm32_epilogue(acc0, acc1, vb, q, m, bias, gain, m2, h3b);
}

// ---- generic MFMA conv (ct-split waves) for layers 4/5, fp32 out + bias ----
template <int G_OUT, int G_IN, int CIN, int COUT, int STRIDE>
__global__ __launch_bounds__(256) void conv_mfma_k(const ushort_t* __restrict__ Ab,
                                                   const ushort_t* __restrict__ Wp,
                                                   const float* __restrict__ bias,
                                                   float* __restrict__ Co)
{
    constexpr int G3 = G_OUT * G_OUT * G_OUT;
    constexpr int NCT = COUT / 16;
    constexpr int NKH = CIN / 32;
    int wave = (blockIdx.x * 256 + threadIdx.x) >> 6;
    int lane = threadIdx.x & 63;
    int ct = wave % NCT;
    int tile = wave / NCT;
    int vb = tile * 16;
    int m = lane & 15;
    int q = lane >> 4;

    int vm = vb + m;
    int b = vm / G3;
    int rr = vm % G3;
    int dm = rr / (G_OUT * G_OUT);
    int hm = (rr / G_OUT) % G_OUT;
    int xm = rr % G_OUT;

    f32x4 acc = {0.f, 0.f, 0.f, 0.f};
    const short8 z8 = {0, 0, 0, 0, 0, 0, 0, 0};

    for (int kd = 0; kd < 3; ++kd) {
        int id = dm * STRIDE + kd - 1;
        for (int kh = 0; kh < 3; ++kh) {
            int ih = hm * STRIDE + kh - 1;
#pragma unroll
            for (int kw = 0; kw < 3; ++kw) {
                int ix = xm * STRIDE + kw - 1;
                bool ok = ((unsigned)id < (unsigned)G_IN) &&
                          ((unsigned)ih < (unsigned)G_IN) &&
                          ((unsigned)ix < (unsigned)G_IN);
                size_t nv = (((size_t)b * G_IN + id) * G_IN + ih) * G_IN + ix;
                const ushort_t* arow = Ab + nv * CIN + q * 8;
                int tap = (kd * 3 + kh) * 3 + kw;
#pragma unroll
                for (int k2 = 0; k2 < NKH; ++k2) {
                    short8 a = ok ? *reinterpret_cast<const short8*>(arow + k2 * 32) : z8;
                    short8 bf = *reinterpret_cast<const short8*>(
                        Wp + (((size_t)(tap * NCT + ct) * NKH + k2) * 64 + lane) * 8);
                    acc = __builtin_amdgcn_mfma_f32_16x16x32_bf16(a, bf, acc, 0, 0, 0);
                }
            }
        }
    }
    int n = ct * 16 + m;
    float bn = bias[n];
#pragma unroll
    for (int i = 0; i < 4; ++i)
        Co[(size_t)(vb + q * 4 + i) * COUT + n] = acc[i] + bn;
}

// ---- AdaNorm+ReLU over 64 channels, mask-aware, fp32->bf16 ----
__global__ __launch_bounds__(256) void norm64_b_k(const float* __restrict__ c,
                                                  const float* __restrict__ mask,
                                                  const float* __restrict__ gain,
                                                  ushort_t* __restrict__ outb, int n)
{
    int t = blockIdx.x * 256 + threadIdx.x;
    if (t >= n) return;
    int v = t >> 6;
    int ch = t & 63;
    float val = c[t];
    float mean = wave_sum64(val) * (1.f / 64.f);
    float dd = val - mean;
    float var = wave_sum64(dd * dd) * (1.f / 64.f) + NEPS;
    float xn = dd * rsqrtf(var);
    float o = fmaxf(gain[ch] * (1.f - K_ADA * xn) * xn, 0.f);
    outb[t] = (mask[v] != 0.f) ? f2b(o) : (ushort_t)0;
}

// ---- AdaNorm+ReLU over 64 channels, mask-aware, fp32 in-place (layer 5) ----
__global__ __launch_bounds__(256) void norm64_f_k(float* __restrict__ c,
                                                  const float* __restrict__ mask,
                                                  const float* __restrict__ gain, int n)
{
    int t = blockIdx.x * 256 + threadIdx.x;
    if (t >= n) return;
    int v = t >> 6;
    int ch = t & 63;
    float val = c[t];
    float mean = wave_sum64(val) * (1.f / 64.f);
    float dd = val - mean;
    float var = wave_sum64(dd * dd) * (1.f / 64.f) + NEPS;
    float xn = dd * rsqrtf(var);
    float o = fmaxf(gain[ch] * (1.f - K_ADA * xn) * xn, 0.f);
    c[t] = (mask[v] != 0.f) ? o : 0.f;
}

// downsample mask: max over 3^3 window, stride 2, pad 1
template <int GO, int GI>
__global__ __launch_bounds__(256) void dmask_k(const float* __restrict__ mi,
                                               float* __restrict__ mo)
{
    constexpr int N = 2 * GO * GO * GO;
    int v = blockIdx.x * 256 + threadIdx.x;
    if (v >= N) return;
    int b = v / (GO * GO * GO);
    int r = v % (GO * GO * GO);
    int d = r / (GO * GO), h = (r / GO) % GO, x = r % GO;
    float mx = 0.f;
    for (int kd = 0; kd < 3; ++kd) {
        int zd = 2 * d + kd - 1; if ((unsigned)zd >= GI) continue;
        for (int kh = 0; kh < 3; ++kh) {
            int zh = 2 * h + kh - 1; if ((unsigned)zh >= GI) continue;
            for (int kw = 0; kw < 3; ++kw) {
                int zx = 2 * x + kw - 1; if ((unsigned)zx >= GI) continue;
                mx = fmaxf(mx, mi[((b * GI + zd) * GI + zh) * GI + zx]);
            }
        }
    }
    mo[v] = mx;
}

// ---- Global max pool stage 1 (h5 >= 0 with zeros at inactive -> plain max) ----
__global__ __launch_bounds__(256) void pool1_k(const float* __restrict__ h5,
                                               float* __restrict__ partials)
{
    int chunk = blockIdx.x % 54;
    int b = blockIdx.x / 54;
    int c = threadIdx.x & 63;
    int s = threadIdx.x >> 6;
    const float* base = h5 + ((size_t)b * 13824 + chunk * 256) * 64;
    float mx = 0.f;
#pragma unroll 4
    for (int v = s; v < 256; v += 4) mx = fmaxf(mx, base[v * 64 + c]);
    __shared__ float red[256];
    red[threadIdx.x] = mx;
    __syncthreads();
    if (s == 0)
        partials[blockIdx.x * 64 + c] =
            fmaxf(fmaxf(red[c], red[64 + c]), fmaxf(red[128 + c], red[192 + c]));
}

// ---- stage 2 + head ----
__global__ __launch_bounds__(128) void pool2_head_k(const float* __restrict__ partials,
                                                    const float* __restrict__ wh,
                                                    const float* __restrict__ bh,
                                                    const float* __restrict__ gh,
                                                    float* __restrict__ out)
{
    __shared__ float pooled[2][64];
    int t = threadIdx.x;
    int b = t >> 6;
    int f = t & 63;
    float mx = 0.f;
    for (int p = 0; p < 54; ++p) mx = fmaxf(mx, partials[(b * 54 + p) * 64 + f]);
    pooled[b][f] = mx;
    __syncthreads();
    float acc = bh[f];
#pragma unroll
    for (int k = 0; k < 64; ++k) acc += pooled[b][k] * wh[k * 64 + f];
    float mean = wave_sum64(acc) * (1.f / 64.f);
    float dd = acc - mean;
    float var = wave_sum64(dd * dd) * (1.f / 64.f) + NEPS;
    float xn = dd * rsqrtf(var);
    float val = gh[f] * (1.f - K_ADA * xn) * xn;
    out[t] = fmaxf(val, 0.f);
}

extern "C" void kernel_launch(void* const* d_in, const int* in_sizes, int n_in,
                              void* d_out, int out_size, void* d_ws, size_t ws_size,
                              hipStream_t stream)
{
    const float* x  = (const float*)d_in[0];
    const float* m1 = (const float*)d_in[1];
    const float* w1 = (const float*)d_in[2];
    const float* b1 = (const float*)d_in[3];
    const float* g1 = (const float*)d_in[4];
    const float* w2 = (const float*)d_in[5];
    const float* b2 = (const float*)d_in[6];
    const float* g2 = (const float*)d_in[7];
    const float* w3 = (const float*)d_in[8];
    const float* b3 = (const float*)d_in[9];
    const float* g3 = (const float*)d_in[10];
    const float* w4 = (const float*)d_in[11];
    const float* b4 = (const float*)d_in[12];
    const float* g4 = (const float*)d_in[13];
    const float* w5 = (const float*)d_in[14];
    const float* b5 = (const float*)d_in[15];
    const float* g5 = (const float*)d_in[16];
    const float* wh = (const float*)d_in[17];
    const float* bh = (const float*)d_in[18];
    const float* gh = (const float*)d_in[19];
    float* out = (float*)d_out;

    // workspace layout (float units; all 16B aligned)
    float* ws = (float*)d_ws;
    ushort_t* h1b = (ushort_t*)ws;                 // 28,311,552 u = 14,155,776 f
    ushort_t* h2b = (ushort_t*)(ws + 14155776);    //  7,077,888 u =  3,538,944 f
    ushort_t* h3b = (ushort_t*)(ws + 17694720);    //  7,077,888 u =  3,538,944 f
    float* c4 = ws + 21233664;                     //  1,769,472 f
    ushort_t* h4b = (ushort_t*)(ws + 23003136);    //  1,769,472 u =    884,736 f
    float* c5 = ws + 23887872;                     //  1,769,472 f
    float* m2 = ws + 25657344;                     //    221,184 f
    float* m3 = ws + 25878528;                     //     27,648 f
    float* partials = ws + 25906176;               //      6,912 f
    ushort_t* wp2 = (ushort_t*)(ws + 25913088);    //  14,336 u = 7,168 f
    ushort_t* wp3 = (ushort_t*)(ws + 25920256);    //  27,648 u = 13,824 f
    ushort_t* wp4 = (ushort_t*)(ws + 25934080);    //  55,296 u = 27,648 f
    ushort_t* wp5 = (ushort_t*)(ws + 25961728);    // 110,592 u = 55,296 f

    // weight packing
    pack_w2_k<<<56, 256, 0, stream>>>(w2, wp2);
    pack_w_k<32, 32><<<108, 256, 0, stream>>>(w3, wp3);
    pack_w_k<32, 64><<<216, 256, 0, stream>>>(w4, wp4);
    pack_w_k<64, 64><<<432, 256, 0, stream>>>(w5, wp5);

    // masks
    dmask_k<48, 96><<<864, 256, 0, stream>>>(m1, m2);
    dmask_k<24, 48><<<108, 256, 0, stream>>>(m2, m3);

    // layer 1: dense scalar conv + norm -> bf16 dense
    conv1_k<<<6912, 256, 0, stream>>>(x, m1, w1, b1, g1, h1b);
    // layer 2: MFMA (tap pairs) + fused norm -> bf16 dense; 13824 waves
    conv2_mfma_k<<<3456, 256, 0, stream>>>(h1b, wp2, b2, g2, m2, h2b);
    // layer 3: MFMA + fused norm -> bf16 dense; 13824 waves
    conv3_mfma_k<<<3456, 256, 0, stream>>>(h2b, wp3, b3, g3, m2, h3b);
    // layer 4: MFMA (ct-split, 6912 waves) + separate norm
    conv_mfma_k<24, 48, 32, 64, 2><<<1728, 256, 0, stream>>>(h3b, wp4, b4, c4);
    norm64_b_k<<<6912, 256, 0, stream>>>(c4, m3, g4, h4b, 1769472);
    // layer 5: MFMA (ct-split, 6912 waves) + separate norm (fp32 out for pool)
    conv_mfma_k<24, 24, 64, 64, 1><<<1728, 256, 0, stream>>>(h4b, wp5, b5, c5);
    norm64_f_k<<<6912, 256, 0, stream>>>(c5, m3, g5, 1769472);

    // pool + head
    pool1_k<<<108, 256, 0, stream>>>(c5, partials);
    pool2_head_k<<<1, 128, 0, stream>>>(partials, wh, bh, gh, out);
}

// Round 5
// 345.072 us; speedup vs baseline: 9.0083x; 1.0439x over previous
//
#include <hip/hip_runtime.h>
#include <math.h>

#define K_ADA 0.1f
#define NEPS 1e-5f

typedef __attribute__((ext_vector_type(8))) short short8;
typedef __attribute__((ext_vector_type(4))) float f32x4;
typedef unsigned short ushort_t;

__device__ __forceinline__ ushort_t f2b(float f) {
    union { float f; unsigned u; } v; v.f = f;
    unsigned r = (v.u + 0x7fffu + ((v.u >> 16) & 1u)) >> 16;
    return (ushort_t)r;
}

__device__ __forceinline__ float wave_sum64(float v) {
#pragma unroll
    for (int m = 1; m < 64; m <<= 1) v += __shfl_xor(v, m, 64);
    return v;
}

// ---- pack weights [3,3,3,CIN,COUT] fp32 -> MFMA B-fragment-ordered bf16 ----
// dst[(((tap*(COUT/16)+ct)*(CIN/32)+kh)*64+lane)*8+jj]
//   = W[tap][kh*32+(lane>>4)*8+jj][ct*16+(lane&15)]
template <int CIN, int COUT>
__global__ __launch_bounds__(256) void pack_w_k(const float* __restrict__ w,
                                                ushort_t* __restrict__ wp)
{
    constexpr int TOTAL = 27 * CIN * COUT;
    int t = blockIdx.x * 256 + threadIdx.x;
    if (t >= TOTAL) return;
    constexpr int NKH = CIN / 32;
    constexpr int NCT = COUT / 16;
    int jj = t & 7;
    int lane = (t >> 3) & 63;
    int rest = t >> 9;              // (tap*NCT + ct)*NKH + kh
    int kh = rest % NKH;
    int rest2 = rest / NKH;
    int ct = rest2 % NCT;
    int tap = rest2 / NCT;
    int cin = kh * 32 + (lane >> 4) * 8 + jj;
    int cout = ct * 16 + (lane & 15);
    wp[t] = f2b(w[(tap * CIN + cin) * COUT + cout]);
}

// ---- pack w1 [27][1][16] -> single B frag, K=taps (pad 32), N=16 couts ----
// dst[lane*8+jj] = W1[(lane>>4)*8+jj][lane&15]  (0 for tap>=27)
__global__ __launch_bounds__(256) void pack_w1_k(const float* __restrict__ w,
                                                 ushort_t* __restrict__ wp)
{
    int t = blockIdx.x * 256 + threadIdx.x;
    if (t >= 512) return;
    int jj = t & 7;
    int lane = t >> 3;
    int tap = (lane >> 4) * 8 + jj;
    int cout = lane & 15;
    wp[t] = (tap < 27) ? f2b(w[tap * 16 + cout]) : (ushort_t)0;
}

// ---- pack w2 [27][16][32] -> tap-paired B frags: 14 pairs x 2 ct ----
// dst[((p*2+ct)*64+lane)*8+jj] = W2[2p+(lane>>5)][((lane>>4)&1)*8+jj][ct*16+(lane&15)]
__global__ __launch_bounds__(256) void pack_w2_k(const float* __restrict__ w,
                                                 ushort_t* __restrict__ wp)
{
    constexpr int TOTAL = 14 * 2 * 64 * 8;  // 14336
    int t = blockIdx.x * 256 + threadIdx.x;
    if (t >= TOTAL) return;
    int jj = t & 7;
    int lane = (t >> 3) & 63;
    int rest = t >> 9;              // p*2 + ct
    int ct = rest & 1;
    int p = rest >> 1;
    int tap = 2 * p + (lane >> 5);
    int cin = ((lane >> 4) & 1) * 8 + jj;
    int cout = ct * 16 + (lane & 15);
    wp[t] = (tap < 27) ? f2b(w[(tap * 16 + cin) * 32 + cout]) : (ushort_t)0;
}

// ---- layer 1 MFMA: 1->16, s=1. Wave = 16-voxel tile. K = 27 taps (pad 32). ----
// x is premasked (exact zeros at inactive) -> dense gather is exact.
// 44% of tiles are all-inactive -> fast zero-store path.
__global__ __launch_bounds__(256) void conv1_mfma_k(const float* __restrict__ x,
                                                    const float* __restrict__ m1,
                                                    const ushort_t* __restrict__ wp1,
                                                    const float* __restrict__ bias,
                                                    const float* __restrict__ gain,
                                                    ushort_t* __restrict__ h1b)
{
    constexpr int G = 96, G3 = G * G * G;
    int wave = (blockIdx.x * 256 + threadIdx.x) >> 6;
    int lane = threadIdx.x & 63;
    int m = lane & 15, q = lane >> 4;
    int vb = wave * 16;
    int vm = vb + m;
    int b = vm / G3;
    int rr = vm % G3;
    int dm = rr / (G * G), hm = (rr / G) % G, xm = rr % G;

    bool act = (m1[vm] != 0.f);
    if (!__any(act)) {
        // whole tile inactive: 16 vox * 16 ch * 2B = 512 B of zeros, 8 B/lane
        reinterpret_cast<unsigned long long*>(h1b + (size_t)vb * 16)[lane] = 0ull;
        return;
    }

    ushort_t av[8];
#pragma unroll
    for (int j = 0; j < 8; ++j) {
        int k = q * 8 + j;
        float xv = 0.f;
        if (k < 27) {
            int kd = k / 9, kh = (k / 3) % 3, kw = k % 3;
            int id = dm + kd - 1, ih = hm + kh - 1, ix = xm + kw - 1;
            if ((unsigned)id < (unsigned)G && (unsigned)ih < (unsigned)G &&
                (unsigned)ix < (unsigned)G)
                xv = x[((b * G + id) * G + ih) * G + ix];
        }
        av[j] = f2b(xv);
    }
    short8 a = *reinterpret_cast<short8*>(av);
    short8 bfr = *reinterpret_cast<const short8*>(wp1 + lane * 8);
    f32x4 acc = {0.f, 0.f, 0.f, 0.f};
    acc = __builtin_amdgcn_mfma_f32_16x16x32_bf16(a, bfr, acc, 0, 0, 0);

    // norm over 16 channels: C/D col = lane&15 = cout, row = q*4+i = voxel
    float bn = bias[m], gn = gain[m];
#pragma unroll
    for (int i = 0; i < 4; ++i) {
        int w = vb + q * 4 + i;
        float xv = acc[i] + bn;
        float s = xv;
#pragma unroll
        for (int mk = 1; mk < 16; mk <<= 1) s += __shfl_xor(s, mk, 64);
        float mean = s * (1.f / 16.f);
        float dd = xv - mean;
        float ss = dd * dd;
#pragma unroll
        for (int mk = 1; mk < 16; mk <<= 1) ss += __shfl_xor(ss, mk, 64);
        float rs = rsqrtf(ss * (1.f / 16.f) + NEPS);
        float xn = dd * rs;
        float o = fmaxf(gn * (1.f - K_ADA * xn) * xn, 0.f);
        h1b[(size_t)w * 16 + m] = (m1[w] != 0.f) ? f2b(o) : (ushort_t)0;
    }
}

// ---- fused 32-channel AdaNorm+ReLU epilogue (wave: 16 voxels x 32 couts) ----
__device__ __forceinline__ void norm32_epilogue(
    f32x4 acc0, f32x4 acc1, int vb, int q, int n,
    const float* __restrict__ bias, const float* __restrict__ gain,
    const float* __restrict__ mask, ushort_t* __restrict__ outb)
{
    float b0 = bias[n], b1 = bias[16 + n];
    float g0 = gain[n], g1 = gain[16 + n];
#pragma unroll
    for (int i = 0; i < 4; ++i) {
        int w = vb + q * 4 + i;
        float x0 = acc0[i] + b0;
        float x1 = acc1[i] + b1;
        float s = x0 + x1;
#pragma unroll
        for (int mk = 1; mk < 16; mk <<= 1) s += __shfl_xor(s, mk, 64);
        float mean = s * (1.f / 32.f);
        float d0 = x0 - mean, d1 = x1 - mean;
        float ss = d0 * d0 + d1 * d1;
#pragma unroll
        for (int mk = 1; mk < 16; mk <<= 1) ss += __shfl_xor(ss, mk, 64);
        float rs = rsqrtf(ss * (1.f / 32.f) + NEPS);
        float mv = mask[w];
        float xn0 = d0 * rs, xn1 = d1 * rs;
        float o0 = fmaxf(g0 * (1.f - K_ADA * xn0) * xn0, 0.f);
        float o1 = fmaxf(g1 * (1.f - K_ADA * xn1) * xn1, 0.f);
        if (mv == 0.f) { o0 = 0.f; o1 = 0.f; }
        outb[(size_t)w * 32 + n]      = f2b(o0);
        outb[(size_t)w * 32 + 16 + n] = f2b(o1);
    }
}

// ---- layer 2 MFMA: 16->32, s=2, K=32 = tap pair. Wave = 32 voxels x 32 couts ----
__global__ __launch_bounds__(256) void conv2_mfma_k(
    const ushort_t* __restrict__ h1b, const ushort_t* __restrict__ wp2,
    const float* __restrict__ bias, const float* __restrict__ gain,
    const float* __restrict__ m2, ushort_t* __restrict__ h2b)
{
    constexpr int G = 48, GI = 96, G3 = G * G * G;
    int wave = (blockIdx.x * 256 + threadIdx.x) >> 6;
    int lane = threadIdx.x & 63;
    int m = lane & 15, q = lane >> 4;
    int vb = wave * 32;
    int tq = q >> 1;   // tap within pair
    int hq = q & 1;    // cin half

    int vmA = vb + m, vmB = vb + 16 + m;
    int bA = vmA / G3, rA = vmA % G3;
    int dA = rA / (G * G), hA = (rA / G) % G, xA = rA % G;
    int bB = vmB / G3, rB = vmB % G3;
    int dB = rB / (G * G), hB = (rB / G) % G, xB = rB % G;

    f32x4 acc00 = {0.f, 0.f, 0.f, 0.f}, acc01 = acc00, acc10 = acc00, acc11 = acc00;
    const short8 z8 = {0, 0, 0, 0, 0, 0, 0, 0};
#pragma unroll
    for (int p = 0; p < 14; ++p) {
        int tap = 2 * p + tq;
        int kd = tap / 9, kh = (tap / 3) % 3, kw = tap % 3;
        int idA = 2 * dA + kd - 1, ihA = 2 * hA + kh - 1, ixA = 2 * xA + kw - 1;
        int idB = 2 * dB + kd - 1, ihB = 2 * hB + kh - 1, ixB = 2 * xB + kw - 1;
        bool okA = (tap < 27) && ((unsigned)idA < (unsigned)GI) &&
                   ((unsigned)ihA < (unsigned)GI) && ((unsigned)ixA < (unsigned)GI);
        bool okB = (tap < 27) && ((unsigned)idB < (unsigned)GI) &&
                   ((unsigned)ihB < (unsigned)GI) && ((unsigned)ixB < (unsigned)GI);
        size_t nvA = (((size_t)bA * GI + idA) * GI + ihA) * GI + ixA;
        size_t nvB = (((size_t)bB * GI + idB) * GI + ihB) * GI + ixB;
        short8 a0 = okA ? *reinterpret_cast<const short8*>(h1b + nvA * 16 + hq * 8) : z8;
        short8 a1 = okB ? *reinterpret_cast<const short8*>(h1b + nvB * 16 + hq * 8) : z8;
        short8 bv0 = *reinterpret_cast<const short8*>(wp2 + ((size_t)(p * 2 + 0) * 64 + lane) * 8);
        short8 bv1 = *reinterpret_cast<const short8*>(wp2 + ((size_t)(p * 2 + 1) * 64 + lane) * 8);
        acc00 = __builtin_amdgcn_mfma_f32_16x16x32_bf16(a0, bv0, acc00, 0, 0, 0);
        acc01 = __builtin_amdgcn_mfma_f32_16x16x32_bf16(a0, bv1, acc01, 0, 0, 0);
        acc10 = __builtin_amdgcn_mfma_f32_16x16x32_bf16(a1, bv0, acc10, 0, 0, 0);
        acc11 = __builtin_amdgcn_mfma_f32_16x16x32_bf16(a1, bv1, acc11, 0, 0, 0);
    }
    norm32_epilogue(acc00, acc01, vb,      q, m, bias, gain, m2, h2b);
    norm32_epilogue(acc10, acc11, vb + 16, q, m, bias, gain, m2, h2b);
}

// ---- layer 3 MFMA: 32->32, s=1, one tap per MFMA. Wave = 32 voxels x 32 couts ----
__global__ __launch_bounds__(256) void conv3_mfma_k(
    const ushort_t* __restrict__ h2b, const ushort_t* __restrict__ wp3,
    const float* __restrict__ bias, const float* __restrict__ gain,
    const float* __restrict__ m2, ushort_t* __restrict__ h3b)
{
    constexpr int G = 48, G3 = G * G * G;
    int wave = (blockIdx.x * 256 + threadIdx.x) >> 6;
    int lane = threadIdx.x & 63;
    int m = lane & 15, q = lane >> 4;
    int vb = wave * 32;

    int vmA = vb + m, vmB = vb + 16 + m;
    int bA = vmA / G3, rA = vmA % G3;
    int dA = rA / (G * G), hA = (rA / G) % G, xA = rA % G;
    int bB = vmB / G3, rB = vmB % G3;
    int dB = rB / (G * G), hB = (rB / G) % G, xB = rB % G;

    f32x4 acc00 = {0.f, 0.f, 0.f, 0.f}, acc01 = acc00, acc10 = acc00, acc11 = acc00;
    const short8 z8 = {0, 0, 0, 0, 0, 0, 0, 0};
    for (int kd = 0; kd < 3; ++kd) {
        for (int kh = 0; kh < 3; ++kh) {
#pragma unroll
            for (int kw = 0; kw < 3; ++kw) {
                int idA = dA + kd - 1, ihA = hA + kh - 1, ixA = xA + kw - 1;
                int idB = dB + kd - 1, ihB = hB + kh - 1, ixB = xB + kw - 1;
                bool okA = ((unsigned)idA < (unsigned)G) && ((unsigned)ihA < (unsigned)G) &&
                           ((unsigned)ixA < (unsigned)G);
                bool okB = ((unsigned)idB < (unsigned)G) && ((unsigned)ihB < (unsigned)G) &&
                           ((unsigned)ixB < (unsigned)G);
                size_t nvA = (((size_t)bA * G + idA) * G + ihA) * G + ixA;
                size_t nvB = (((size_t)bB * G + idB) * G + ihB) * G + ixB;
                int tap = (kd * 3 + kh) * 3 + kw;
                short8 a0 = okA ? *reinterpret_cast<const short8*>(h2b + nvA * 32 + q * 8) : z8;
                short8 a1 = okB ? *reinterpret_cast<const short8*>(h2b + nvB * 32 + q * 8) : z8;
                short8 bv0 = *reinterpret_cast<const short8*>(wp3 + ((size_t)(tap * 2 + 0) * 64 + lane) * 8);
                short8 bv1 = *reinterpret_cast<const short8*>(wp3 + ((size_t)(tap * 2 + 1) * 64 + lane) * 8);
                acc00 = __builtin_amdgcn_mfma_f32_16x16x32_bf16(a0, bv0, acc00, 0, 0, 0);
                acc01 = __builtin_amdgcn_mfma_f32_16x16x32_bf16(a0, bv1, acc01, 0, 0, 0);
                acc10 = __builtin_amdgcn_mfma_f32_16x16x32_bf16(a1, bv0, acc10, 0, 0, 0);
                acc11 = __builtin_amdgcn_mfma_f32_16x16x32_bf16(a1, bv1, acc11, 0, 0, 0);
            }
        }
    }
    norm32_epilogue(acc00, acc01, vb,      q, m, bias, gain, m2, h3b);
    norm32_epilogue(acc10, acc11, vb + 16, q, m, bias, gain, m2, h3b);
}

// ---- layers 4/5: block = 4 ct-waves of one 16-voxel tile; fused 64-ch norm ----
// OUTB: write bf16 (layer 4) else fp32 (layer 5, feeds pool).
template <int G_IN, int CIN, int STRIDE, bool OUTB>
__global__ __launch_bounds__(256) void conv45_k(const ushort_t* __restrict__ Ab,
                                                const ushort_t* __restrict__ Wp,
                                                const float* __restrict__ bias,
                                                const float* __restrict__ gain,
                                                const float* __restrict__ mask,
                                                ushort_t* __restrict__ outb,
                                                float* __restrict__ outf)
{
    constexpr int G = 24, G3 = G * G * G;
    constexpr int NKH = CIN / 32;
    int ct = threadIdx.x >> 6;
    int lane = threadIdx.x & 63;
    int m = lane & 15, q = lane >> 4;
    int vb = blockIdx.x * 16;
    int vm = vb + m;
    int b = vm / G3;
    int rr = vm % G3;
    int dm = rr / (G * G), hm = (rr / G) % G, xm = rr % G;

    f32x4 acc = {0.f, 0.f, 0.f, 0.f};
    const short8 z8 = {0, 0, 0, 0, 0, 0, 0, 0};
    for (int kd = 0; kd < 3; ++kd) {
        int id = dm * STRIDE + kd - 1;
        for (int kh = 0; kh < 3; ++kh) {
            int ih = hm * STRIDE + kh - 1;
#pragma unroll
            for (int kw = 0; kw < 3; ++kw) {
                int ix = xm * STRIDE + kw - 1;
                bool ok = ((unsigned)id < (unsigned)G_IN) &&
                          ((unsigned)ih < (unsigned)G_IN) &&
                          ((unsigned)ix < (unsigned)G_IN);
                size_t nv = (((size_t)b * G_IN + id) * G_IN + ih) * G_IN + ix;
                const ushort_t* arow = Ab + nv * CIN + q * 8;
                int tap = (kd * 3 + kh) * 3 + kw;
#pragma unroll
                for (int k2 = 0; k2 < NKH; ++k2) {
                    short8 a = ok ? *reinterpret_cast<const short8*>(arow + k2 * 32) : z8;
                    short8 bf = *reinterpret_cast<const short8*>(
                        Wp + (((size_t)(tap * 4 + ct) * NKH + k2) * 64 + lane) * 8);
                    acc = __builtin_amdgcn_mfma_f32_16x16x32_bf16(a, bf, acc, 0, 0, 0);
                }
            }
        }
    }

    __shared__ float lds[16][64];
    float bn = bias[ct * 16 + m];
#pragma unroll
    for (int i = 0; i < 4; ++i) lds[q * 4 + i][ct * 16 + m] = acc[i] + bn;
    __syncthreads();

    float gn = gain[lane];
#pragma unroll
    for (int i = 0; i < 4; ++i) {
        int vloc = ct * 4 + i;
        int w = vb + vloc;
        float val = lds[vloc][lane];
        float mean = wave_sum64(val) * (1.f / 64.f);
        float dd = val - mean;
        float var = wave_sum64(dd * dd) * (1.f / 64.f) + NEPS;
        float xn = dd * rsqrtf(var);
        float o = fmaxf(gn * (1.f - K_ADA * xn) * xn, 0.f);
        if (mask[w] == 0.f) o = 0.f;
        if (OUTB) outb[(size_t)w * 64 + lane] = f2b(o);
        else      outf[(size_t)w * 64 + lane] = o;
    }
}

// downsample mask: max over 3^3 window, stride 2, pad 1
template <int GO, int GI>
__global__ __launch_bounds__(256) void dmask_k(const float* __restrict__ mi,
                                               float* __restrict__ mo)
{
    constexpr int N = 2 * GO * GO * GO;
    int v = blockIdx.x * 256 + threadIdx.x;
    if (v >= N) return;
    int b = v / (GO * GO * GO);
    int r = v % (GO * GO * GO);
    int d = r / (GO * GO), h = (r / GO) % GO, x = r % GO;
    float mx = 0.f;
    for (int kd = 0; kd < 3; ++kd) {
        int zd = 2 * d + kd - 1; if ((unsigned)zd >= GI) continue;
        for (int kh = 0; kh < 3; ++kh) {
            int zh = 2 * h + kh - 1; if ((unsigned)zh >= GI) continue;
            for (int kw = 0; kw < 3; ++kw) {
                int zx = 2 * x + kw - 1; if ((unsigned)zx >= GI) continue;
                mx = fmaxf(mx, mi[((b * GI + zd) * GI + zh) * GI + zx]);
            }
        }
    }
    mo[v] = mx;
}

// ---- Global max pool stage 1 (h5 >= 0 with zeros at inactive -> plain max) ----
__global__ __launch_bounds__(256) void pool1_k(const float* __restrict__ h5,
                                               float* __restrict__ partials)
{
    int chunk = blockIdx.x % 54;
    int b = blockIdx.x / 54;
    int c = threadIdx.x & 63;
    int s = threadIdx.x >> 6;
    const float* base = h5 + ((size_t)b * 13824 + chunk * 256) * 64;
    float mx = 0.f;
#pragma unroll 4
    for (int v = s; v < 256; v += 4) mx = fmaxf(mx, base[v * 64 + c]);
    __shared__ float red[256];
    red[threadIdx.x] = mx;
    __syncthreads();
    if (s == 0)
        partials[blockIdx.x * 64 + c] =
            fmaxf(fmaxf(red[c], red[64 + c]), fmaxf(red[128 + c], red[192 + c]));
}

// ---- stage 2 + head ----
__global__ __launch_bounds__(128) void pool2_head_k(const float* __restrict__ partials,
                                                    const float* __restrict__ wh,
                                                    const float* __restrict__ bh,
                                                    const float* __restrict__ gh,
                                                    float* __restrict__ out)
{
    __shared__ float pooled[2][64];
    int t = threadIdx.x;
    int b = t >> 6;
    int f = t & 63;
    float mx = 0.f;
    for (int p = 0; p < 54; ++p) mx = fmaxf(mx, partials[(b * 54 + p) * 64 + f]);
    pooled[b][f] = mx;
    __syncthreads();
    float acc = bh[f];
#pragma unroll
    for (int k = 0; k < 64; ++k) acc += pooled[b][k] * wh[k * 64 + f];
    float mean = wave_sum64(acc) * (1.f / 64.f);
    float dd = acc - mean;
    float var = wave_sum64(dd * dd) * (1.f / 64.f) + NEPS;
    float xn = dd * rsqrtf(var);
    float val = gh[f] * (1.f - K_ADA * xn) * xn;
    out[t] = fmaxf(val, 0.f);
}

extern "C" void kernel_launch(void* const* d_in, const int* in_sizes, int n_in,
                              void* d_out, int out_size, void* d_ws, size_t ws_size,
                              hipStream_t stream)
{
    const float* x  = (const float*)d_in[0];
    const float* m1 = (const float*)d_in[1];
    const float* w1 = (const float*)d_in[2];
    const float* b1 = (const float*)d_in[3];
    const float* g1 = (const float*)d_in[4];
    const float* w2 = (const float*)d_in[5];
    const float* b2 = (const float*)d_in[6];
    const float* g2 = (const float*)d_in[7];
    const float* w3 = (const float*)d_in[8];
    const float* b3 = (const float*)d_in[9];
    const float* g3 = (const float*)d_in[10];
    const float* w4 = (const float*)d_in[11];
    const float* b4 = (const float*)d_in[12];
    const float* g4 = (const float*)d_in[13];
    const float* w5 = (const float*)d_in[14];
    const float* b5 = (const float*)d_in[15];
    const float* g5 = (const float*)d_in[16];
    const float* wh = (const float*)d_in[17];
    const float* bh = (const float*)d_in[18];
    const float* gh = (const float*)d_in[19];
    float* out = (float*)d_out;

    // workspace layout (float units; all 16B aligned)
    float* ws = (float*)d_ws;
    ushort_t* h1b = (ushort_t*)ws;                 // 28,311,552 u = 14,155,776 f
    ushort_t* h2b = (ushort_t*)(ws + 14155776);    //  7,077,888 u =  3,538,944 f
    ushort_t* h3b = (ushort_t*)(ws + 17694720);    //  7,077,888 u =  3,538,944 f
    ushort_t* h4b = (ushort_t*)(ws + 21233664);    //  1,769,472 u =    884,736 f
    float* h5 = ws + 22118400;                     //  1,769,472 f
    float* m2 = ws + 23887872;                     //    221,184 f
    float* m3 = ws + 24109056;                     //     27,648 f
    float* partials = ws + 24136704;               //      6,912 f
    ushort_t* wp1 = (ushort_t*)(ws + 24143616);    //     512 u =    256 f
    ushort_t* wp2 = (ushort_t*)(ws + 24143872);    //  14,336 u =  7,168 f
    ushort_t* wp3 = (ushort_t*)(ws + 24151040);    //  27,648 u = 13,824 f
    ushort_t* wp4 = (ushort_t*)(ws + 24164864);    //  55,296 u = 27,648 f
    ushort_t* wp5 = (ushort_t*)(ws + 24192512);    // 110,592 u = 55,296 f

    // weight packing
    pack_w1_k<<<2, 256, 0, stream>>>(w1, wp1);
    pack_w2_k<<<56, 256, 0, stream>>>(w2, wp2);
    pack_w_k<32, 32><<<108, 256, 0, stream>>>(w3, wp3);
    pack_w_k<32, 64><<<216, 256, 0, stream>>>(w4, wp4);
    pack_w_k<64, 64><<<432, 256, 0, stream>>>(w5, wp5);

    // masks
    dmask_k<48, 96><<<864, 256, 0, stream>>>(m1, m2);
    dmask_k<24, 48><<<108, 256, 0, stream>>>(m2, m3);

    // layer 1: MFMA tile conv + fused norm16; 110592 waves -> 27648 blocks
    conv1_mfma_k<<<27648, 256, 0, stream>>>(x, m1, wp1, b1, g1, h1b);
    // layer 2: MFMA (tap pairs, 32-voxel tiles) + fused norm; 6912 waves
    conv2_mfma_k<<<1728, 256, 0, stream>>>(h1b, wp2, b2, g2, m2, h2b);
    // layer 3: MFMA (32-voxel tiles) + fused norm; 6912 waves
    conv3_mfma_k<<<1728, 256, 0, stream>>>(h2b, wp3, b3, g3, m2, h3b);
    // layer 4: MFMA + block-fused 64-ch norm -> bf16
    conv45_k<48, 32, 2, true><<<1728, 256, 0, stream>>>(h3b, wp4, b4, g4, m3, h4b, nullptr);
    // layer 5: MFMA + block-fused 64-ch norm -> fp32 (feeds pool)
    conv45_k<24, 64, 1, false><<<1728, 256, 0, stream>>>(h4b, wp5, b5, g5, m3, nullptr, h5);

    // pool + head
    pool1_k<<<108, 256, 0, stream>>>(h5, partials);
    pool2_head_k<<<1, 128, 0, stream>>>(partials, wh, bh, gh, out);
}

// Round 6
// 326.772 us; speedup vs baseline: 9.5128x; 1.0560x over previous
//
#include <hip/hip_runtime.h>
#include <math.h>

#define K_ADA 0.1f
#define NEPS 1e-5f

typedef __attribute__((ext_vector_type(8))) short short8;
typedef __attribute__((ext_vector_type(4))) float f32x4;
typedef unsigned short ushort_t;

__device__ __forceinline__ ushort_t f2b(float f) {
    union { float f; unsigned u; } v; v.f = f;
    unsigned r = (v.u + 0x7fffu + ((v.u >> 16) & 1u)) >> 16;
    return (ushort_t)r;
}

__device__ __forceinline__ float wave_sum64(float v) {
#pragma unroll
    for (int m = 1; m < 64; m <<= 1) v += __shfl_xor(v, m, 64);
    return v;
}

// ---- generic pack element: [3,3,3,CIN,COUT] fp32 -> B-fragment bf16 ----
template <int CIN, int COUT>
__device__ __forceinline__ void pack_w_el(const float* __restrict__ w,
                                          ushort_t* __restrict__ wp, int t)
{
    constexpr int NKH = CIN / 32;
    constexpr int NCT = COUT / 16;
    int jj = t & 7;
    int lane = (t >> 3) & 63;
    int rest = t >> 9;              // (tap*NCT + ct)*NKH + kh
    int kh = rest % NKH;
    int rest2 = rest / NKH;
    int ct = rest2 % NCT;
    int tap = rest2 / NCT;
    int cin = kh * 32 + (lane >> 4) * 8 + jj;
    int cout = ct * 16 + (lane & 15);
    wp[t] = f2b(w[(tap * CIN + cin) * COUT + cout]);
}

// ---- merged prep: pack w1..w5 + dmask m1->m2, one launch ----
__global__ __launch_bounds__(256) void prep_k(
    const float* __restrict__ w1, const float* __restrict__ w2,
    const float* __restrict__ w3, const float* __restrict__ w4,
    const float* __restrict__ w5, const float* __restrict__ m1,
    ushort_t* __restrict__ wp1, ushort_t* __restrict__ wp2,
    ushort_t* __restrict__ wp3, ushort_t* __restrict__ wp4,
    ushort_t* __restrict__ wp5, float* __restrict__ m2)
{
    int t = blockIdx.x * 256 + threadIdx.x;
    if (t < 512) {
        // w1 [27][1][16] -> single frag, K=taps (pad 32)
        int jj = t & 7;
        int lane = t >> 3;
        int tap = (lane >> 4) * 8 + jj;
        int cout = lane & 15;
        wp1[t] = (tap < 27) ? f2b(w1[tap * 16 + cout]) : (ushort_t)0;
    } else if (t < 14848) {
        // w2 [27][16][32] -> tap-paired frags: 14 pairs x 2 ct
        int u = t - 512;
        int jj = u & 7;
        int lane = (u >> 3) & 63;
        int rest = u >> 9;
        int ct = rest & 1;
        int p = rest >> 1;
        int tap = 2 * p + (lane >> 5);
        int cin = ((lane >> 4) & 1) * 8 + jj;
        int cout = ct * 16 + (lane & 15);
        wp2[u] = (tap < 27) ? f2b(w2[(tap * 16 + cin) * 32 + cout]) : (ushort_t)0;
    } else if (t < 42496) {
        pack_w_el<32, 32>(w3, wp3, t - 14848);
    } else if (t < 97792) {
        pack_w_el<32, 64>(w4, wp4, t - 42496);
    } else if (t < 208384) {
        pack_w_el<64, 64>(w5, wp5, t - 97792);
    } else if (t < 429568) {
        // dmask 96 -> 48
        int v = t - 208384;
        constexpr int GO = 48, GI = 96;
        int b = v / (GO * GO * GO);
        int r = v % (GO * GO * GO);
        int d = r / (GO * GO), h = (r / GO) % GO, x = r % GO;
        float mx = 0.f;
        for (int kd = 0; kd < 3; ++kd) {
            int zd = 2 * d + kd - 1; if ((unsigned)zd >= GI) continue;
            for (int kh = 0; kh < 3; ++kh) {
                int zh = 2 * h + kh - 1; if ((unsigned)zh >= GI) continue;
                for (int kw = 0; kw < 3; ++kw) {
                    int zx = 2 * x + kw - 1; if ((unsigned)zx >= GI) continue;
                    mx = fmaxf(mx, m1[((b * GI + zd) * GI + zh) * GI + zx]);
                }
            }
        }
        m2[v] = mx;
    }
}

// downsample mask: max over 3^3 window, stride 2, pad 1 (m2 -> m3)
template <int GO, int GI>
__global__ __launch_bounds__(256) void dmask_k(const float* __restrict__ mi,
                                               float* __restrict__ mo)
{
    constexpr int N = 2 * GO * GO * GO;
    int v = blockIdx.x * 256 + threadIdx.x;
    if (v >= N) return;
    int b = v / (GO * GO * GO);
    int r = v % (GO * GO * GO);
    int d = r / (GO * GO), h = (r / GO) % GO, x = r % GO;
    float mx = 0.f;
    for (int kd = 0; kd < 3; ++kd) {
        int zd = 2 * d + kd - 1; if ((unsigned)zd >= GI) continue;
        for (int kh = 0; kh < 3; ++kh) {
            int zh = 2 * h + kh - 1; if ((unsigned)zh >= GI) continue;
            for (int kw = 0; kw < 3; ++kw) {
                int zx = 2 * x + kw - 1; if ((unsigned)zx >= GI) continue;
                mx = fmaxf(mx, mi[((b * GI + zd) * GI + zh) * GI + zx]);
            }
        }
    }
    mo[v] = mx;
}

// ---- layer 1 MFMA: 1->16, s=1. Wave = 16-voxel tile. K = 27 taps (pad 32). ----
__global__ __launch_bounds__(256) void conv1_mfma_k(const float* __restrict__ x,
                                                    const float* __restrict__ m1,
                                                    const ushort_t* __restrict__ wp1,
                                                    const float* __restrict__ bias,
                                                    const float* __restrict__ gain,
                                                    ushort_t* __restrict__ h1b)
{
    constexpr int G = 96, G3 = G * G * G;
    int wave = (blockIdx.x * 256 + threadIdx.x) >> 6;
    int lane = threadIdx.x & 63;
    int m = lane & 15, q = lane >> 4;
    int vb = wave * 16;
    int vm = vb + m;
    int b = vm / G3;
    int rr = vm % G3;
    int dm = rr / (G * G), hm = (rr / G) % G, xm = rr % G;

    bool act = (m1[vm] != 0.f);
    if (!__any(act)) {
        reinterpret_cast<unsigned long long*>(h1b + (size_t)vb * 16)[lane] = 0ull;
        return;
    }

    ushort_t av[8];
#pragma unroll
    for (int j = 0; j < 8; ++j) {
        int k = q * 8 + j;
        float xv = 0.f;
        if (k < 27) {
            int kd = k / 9, kh = (k / 3) % 3, kw = k % 3;
            int id = dm + kd - 1, ih = hm + kh - 1, ix = xm + kw - 1;
            if ((unsigned)id < (unsigned)G && (unsigned)ih < (unsigned)G &&
                (unsigned)ix < (unsigned)G)
                xv = x[((b * G + id) * G + ih) * G + ix];
        }
        av[j] = f2b(xv);
    }
    short8 a = *reinterpret_cast<short8*>(av);
    short8 bfr = *reinterpret_cast<const short8*>(wp1 + lane * 8);
    f32x4 acc = {0.f, 0.f, 0.f, 0.f};
    acc = __builtin_amdgcn_mfma_f32_16x16x32_bf16(a, bfr, acc, 0, 0, 0);

    float bn = bias[m], gn = gain[m];
#pragma unroll
    for (int i = 0; i < 4; ++i) {
        int w = vb + q * 4 + i;
        float xv = acc[i] + bn;
        float s = xv;
#pragma unroll
        for (int mk = 1; mk < 16; mk <<= 1) s += __shfl_xor(s, mk, 64);
        float mean = s * (1.f / 16.f);
        float dd = xv - mean;
        float ss = dd * dd;
#pragma unroll
        for (int mk = 1; mk < 16; mk <<= 1) ss += __shfl_xor(ss, mk, 64);
        float rs = rsqrtf(ss * (1.f / 16.f) + NEPS);
        float xn = dd * rs;
        float o = fmaxf(gn * (1.f - K_ADA * xn) * xn, 0.f);
        h1b[(size_t)w * 16 + m] = (m1[w] != 0.f) ? f2b(o) : (ushort_t)0;
    }
}

// ---- fused 32-channel AdaNorm+ReLU epilogue (wave: 16 voxels x 32 couts) ----
__device__ __forceinline__ void norm32_epilogue(
    f32x4 acc0, f32x4 acc1, int vb, int q, int n,
    const float* __restrict__ bias, const float* __restrict__ gain,
    const float* __restrict__ mask, ushort_t* __restrict__ outb)
{
    float b0 = bias[n], b1 = bias[16 + n];
    float g0 = gain[n], g1 = gain[16 + n];
#pragma unroll
    for (int i = 0; i < 4; ++i) {
        int w = vb + q * 4 + i;
        float x0 = acc0[i] + b0;
        float x1 = acc1[i] + b1;
        float s = x0 + x1;
#pragma unroll
        for (int mk = 1; mk < 16; mk <<= 1) s += __shfl_xor(s, mk, 64);
        float mean = s * (1.f / 32.f);
        float d0 = x0 - mean, d1 = x1 - mean;
        float ss = d0 * d0 + d1 * d1;
#pragma unroll
        for (int mk = 1; mk < 16; mk <<= 1) ss += __shfl_xor(ss, mk, 64);
        float rs = rsqrtf(ss * (1.f / 32.f) + NEPS);
        float mv = mask[w];
        float xn0 = d0 * rs, xn1 = d1 * rs;
        float o0 = fmaxf(g0 * (1.f - K_ADA * xn0) * xn0, 0.f);
        float o1 = fmaxf(g1 * (1.f - K_ADA * xn1) * xn1, 0.f);
        if (mv == 0.f) { o0 = 0.f; o1 = 0.f; }
        outb[(size_t)w * 32 + n]      = f2b(o0);
        outb[(size_t)w * 32 + 16 + n] = f2b(o1);
    }
}

// ---- layer 2 MFMA: 16->32, s=2, K=32 = tap pair. Wave = 32 voxels x 32 couts ----
__global__ __launch_bounds__(256) void conv2_mfma_k(
    const ushort_t* __restrict__ h1b, const ushort_t* __restrict__ wp2,
    const float* __restrict__ bias, const float* __restrict__ gain,
    const float* __restrict__ m2, ushort_t* __restrict__ h2b)
{
    constexpr int G = 48, GI = 96, G3 = G * G * G;
    int wave = (blockIdx.x * 256 + threadIdx.x) >> 6;
    int lane = threadIdx.x & 63;
    int m = lane & 15, q = lane >> 4;
    int vb = wave * 32;
    int tq = q >> 1;   // tap within pair
    int hq = q & 1;    // cin half

    int vmA = vb + m, vmB = vb + 16 + m;
    int bA = vmA / G3, rA = vmA % G3;
    int dA = rA / (G * G), hA = (rA / G) % G, xA = rA % G;
    int bB = vmB / G3, rB = vmB % G3;
    int dB = rB / (G * G), hB = (rB / G) % G, xB = rB % G;

    f32x4 acc00 = {0.f, 0.f, 0.f, 0.f}, acc01 = acc00, acc10 = acc00, acc11 = acc00;
    const short8 z8 = {0, 0, 0, 0, 0, 0, 0, 0};
#pragma unroll
    for (int p = 0; p < 14; ++p) {
        int tap = 2 * p + tq;
        int kd = tap / 9, kh = (tap / 3) % 3, kw = tap % 3;
        int idA = 2 * dA + kd - 1, ihA = 2 * hA + kh - 1, ixA = 2 * xA + kw - 1;
        int idB = 2 * dB + kd - 1, ihB = 2 * hB + kh - 1, ixB = 2 * xB + kw - 1;
        bool okA = (tap < 27) && ((unsigned)idA < (unsigned)GI) &&
                   ((unsigned)ihA < (unsigned)GI) && ((unsigned)ixA < (unsigned)GI);
        bool okB = (tap < 27) && ((unsigned)idB < (unsigned)GI) &&
                   ((unsigned)ihB < (unsigned)GI) && ((unsigned)ixB < (unsigned)GI);
        size_t nvA = (((size_t)bA * GI + idA) * GI + ihA) * GI + ixA;
        size_t nvB = (((size_t)bB * GI + idB) * GI + ihB) * GI + ixB;
        short8 a0 = okA ? *reinterpret_cast<const short8*>(h1b + nvA * 16 + hq * 8) : z8;
        short8 a1 = okB ? *reinterpret_cast<const short8*>(h1b + nvB * 16 + hq * 8) : z8;
        short8 bv0 = *reinterpret_cast<const short8*>(wp2 + ((size_t)(p * 2 + 0) * 64 + lane) * 8);
        short8 bv1 = *reinterpret_cast<const short8*>(wp2 + ((size_t)(p * 2 + 1) * 64 + lane) * 8);
        acc00 = __builtin_amdgcn_mfma_f32_16x16x32_bf16(a0, bv0, acc00, 0, 0, 0);
        acc01 = __builtin_amdgcn_mfma_f32_16x16x32_bf16(a0, bv1, acc01, 0, 0, 0);
        acc10 = __builtin_amdgcn_mfma_f32_16x16x32_bf16(a1, bv0, acc10, 0, 0, 0);
        acc11 = __builtin_amdgcn_mfma_f32_16x16x32_bf16(a1, bv1, acc11, 0, 0, 0);
    }
    norm32_epilogue(acc00, acc01, vb,      q, m, bias, gain, m2, h2b);
    norm32_epilogue(acc10, acc11, vb + 16, q, m, bias, gain, m2, h2b);
}

// ---- layer 3 MFMA: 32->32, s=1, FULL 27-tap unroll. Wave = 32 vox x 32 couts ----
__global__ __launch_bounds__(256, 4) void conv3_mfma_k(
    const ushort_t* __restrict__ h2b, const ushort_t* __restrict__ wp3,
    const float* __restrict__ bias, const float* __restrict__ gain,
    const float* __restrict__ m2, ushort_t* __restrict__ h3b)
{
    constexpr int G = 48, G3 = G * G * G;
    int wave = (blockIdx.x * 256 + threadIdx.x) >> 6;
    int lane = threadIdx.x & 63;
    int m = lane & 15, q = lane >> 4;
    int vb = wave * 32;

    int vmA = vb + m, vmB = vb + 16 + m;
    int bA = vmA / G3, rA = vmA % G3;
    int dA = rA / (G * G), hA = (rA / G) % G, xA = rA % G;
    int bB = vmB / G3, rB = vmB % G3;
    int dB = rB / (G * G), hB = (rB / G) % G, xB = rB % G;

    f32x4 acc00 = {0.f, 0.f, 0.f, 0.f}, acc01 = acc00, acc10 = acc00, acc11 = acc00;
    const short8 z8 = {0, 0, 0, 0, 0, 0, 0, 0};
#pragma unroll
    for (int tap = 0; tap < 27; ++tap) {
        const int kd = tap / 9, kh = (tap / 3) % 3, kw = tap % 3;
        int idA = dA + kd - 1, ihA = hA + kh - 1, ixA = xA + kw - 1;
        int idB = dB + kd - 1, ihB = hB + kh - 1, ixB = xB + kw - 1;
        bool okA = ((unsigned)idA < (unsigned)G) && ((unsigned)ihA < (unsigned)G) &&
                   ((unsigned)ixA < (unsigned)G);
        bool okB = ((unsigned)idB < (unsigned)G) && ((unsigned)ihB < (unsigned)G) &&
                   ((unsigned)ixB < (unsigned)G);
        size_t nvA = (((size_t)bA * G + idA) * G + ihA) * G + ixA;
        size_t nvB = (((size_t)bB * G + idB) * G + ihB) * G + ixB;
        short8 a0 = okA ? *reinterpret_cast<const short8*>(h2b + nvA * 32 + q * 8) : z8;
        short8 a1 = okB ? *reinterpret_cast<const short8*>(h2b + nvB * 32 + q * 8) : z8;
        short8 bv0 = *reinterpret_cast<const short8*>(wp3 + ((size_t)(tap * 2 + 0) * 64 + lane) * 8);
        short8 bv1 = *reinterpret_cast<const short8*>(wp3 + ((size_t)(tap * 2 + 1) * 64 + lane) * 8);
        acc00 = __builtin_amdgcn_mfma_f32_16x16x32_bf16(a0, bv0, acc00, 0, 0, 0);
        acc01 = __builtin_amdgcn_mfma_f32_16x16x32_bf16(a0, bv1, acc01, 0, 0, 0);
        acc10 = __builtin_amdgcn_mfma_f32_16x16x32_bf16(a1, bv0, acc10, 0, 0, 0);
        acc11 = __builtin_amdgcn_mfma_f32_16x16x32_bf16(a1, bv1, acc11, 0, 0, 0);
    }
    norm32_epilogue(acc00, acc01, vb,      q, m, bias, gain, m2, h3b);
    norm32_epilogue(acc10, acc11, vb + 16, q, m, bias, gain, m2, h3b);
}

// ---- layers 4/5: block = 4 ct-waves of one 16-voxel tile; FULL tap unroll ----
template <int G_IN, int CIN, int STRIDE, bool OUTB>
__global__ __launch_bounds__(256, 4) void conv45_k(const ushort_t* __restrict__ Ab,
                                                   const ushort_t* __restrict__ Wp,
                                                   const float* __restrict__ bias,
                                                   const float* __restrict__ gain,
                                                   const float* __restrict__ mask,
                                                   ushort_t* __restrict__ outb,
                                                   float* __restrict__ outf)
{
    constexpr int G = 24, G3 = G * G * G;
    constexpr int NKH = CIN / 32;
    int ct = threadIdx.x >> 6;
    int lane = threadIdx.x & 63;
    int m = lane & 15, q = lane >> 4;
    int vb = blockIdx.x * 16;
    int vm = vb + m;
    int b = vm / G3;
    int rr = vm % G3;
    int dm = rr / (G * G), hm = (rr / G) % G, xm = rr % G;

    f32x4 acc = {0.f, 0.f, 0.f, 0.f};
    const short8 z8 = {0, 0, 0, 0, 0, 0, 0, 0};
#pragma unroll
    for (int tap = 0; tap < 27; ++tap) {
        const int kd = tap / 9, kh = (tap / 3) % 3, kw = tap % 3;
        int id = dm * STRIDE + kd - 1;
        int ih = hm * STRIDE + kh - 1;
        int ix = xm * STRIDE + kw - 1;
        bool ok = ((unsigned)id < (unsigned)G_IN) &&
                  ((unsigned)ih < (unsigned)G_IN) &&
                  ((unsigned)ix < (unsigned)G_IN);
        size_t nv = (((size_t)b * G_IN + id) * G_IN + ih) * G_IN + ix;
        const ushort_t* arow = Ab + nv * CIN + q * 8;
#pragma unroll
        for (int k2 = 0; k2 < NKH; ++k2) {
            short8 a = ok ? *reinterpret_cast<const short8*>(arow + k2 * 32) : z8;
            short8 bf = *reinterpret_cast<const short8*>(
                Wp + (((size_t)(tap * 4 + ct) * NKH + k2) * 64 + lane) * 8);
            acc = __builtin_amdgcn_mfma_f32_16x16x32_bf16(a, bf, acc, 0, 0, 0);
        }
    }

    __shared__ float lds[16][65];  // +1 pad: kills 4-way store conflicts
    float bn = bias[ct * 16 + m];
#pragma unroll
    for (int i = 0; i < 4; ++i) lds[q * 4 + i][ct * 16 + m] = acc[i] + bn;
    __syncthreads();

    float gn = gain[lane];
#pragma unroll
    for (int i = 0; i < 4; ++i) {
        int vloc = ct * 4 + i;
        int w = vb + vloc;
        float val = lds[vloc][lane];
        float mean = wave_sum64(val) * (1.f / 64.f);
        float dd = val - mean;
        float var = wave_sum64(dd * dd) * (1.f / 64.f) + NEPS;
        float xn = dd * rsqrtf(var);
        float o = fmaxf(gn * (1.f - K_ADA * xn) * xn, 0.f);
        if (mask[w] == 0.f) o = 0.f;
        if (OUTB) outb[(size_t)w * 64 + lane] = f2b(o);
        else      outf[(size_t)w * 64 + lane] = o;
    }
}

// ---- Global max pool stage 1 (h5 >= 0 with zeros at inactive -> plain max) ----
__global__ __launch_bounds__(256) void pool1_k(const float* __restrict__ h5,
                                               float* __restrict__ partials)
{
    int chunk = blockIdx.x % 54;
    int b = blockIdx.x / 54;
    int c = threadIdx.x & 63;
    int s = threadIdx.x >> 6;
    const float* base = h5 + ((size_t)b * 13824 + chunk * 256) * 64;
    float mx = 0.f;
#pragma unroll 4
    for (int v = s; v < 256; v += 4) mx = fmaxf(mx, base[v * 64 + c]);
    __shared__ float red[256];
    red[threadIdx.x] = mx;
    __syncthreads();
    if (s == 0)
        partials[blockIdx.x * 64 + c] =
            fmaxf(fmaxf(red[c], red[64 + c]), fmaxf(red[128 + c], red[192 + c]));
}

// ---- stage 2 + head ----
__global__ __launch_bounds__(128) void pool2_head_k(const float* __restrict__ partials,
                                                    const float* __restrict__ wh,
                                                    const float* __restrict__ bh,
                                                    const float* __restrict__ gh,
                                                    float* __restrict__ out)
{
    __shared__ float pooled[2][64];
    int t = threadIdx.x;
    int b = t >> 6;
    int f = t & 63;
    float mx = 0.f;
    for (int p = 0; p < 54; ++p) mx = fmaxf(mx, partials[(b * 54 + p) * 64 + f]);
    pooled[b][f] = mx;
    __syncthreads();
    float acc = bh[f];
#pragma unroll
    for (int k = 0; k < 64; ++k) acc += pooled[b][k] * wh[k * 64 + f];
    float mean = wave_sum64(acc) * (1.f / 64.f);
    float dd = acc - mean;
    float var = wave_sum64(dd * dd) * (1.f / 64.f) + NEPS;
    float xn = dd * rsqrtf(var);
    float val = gh[f] * (1.f - K_ADA * xn) * xn;
    out[t] = fmaxf(val, 0.f);
}

extern "C" void kernel_launch(void* const* d_in, const int* in_sizes, int n_in,
                              void* d_out, int out_size, void* d_ws, size_t ws_size,
                              hipStream_t stream)
{
    const float* x  = (const float*)d_in[0];
    const float* m1 = (const float*)d_in[1];
    const float* w1 = (const float*)d_in[2];
    const float* b1 = (const float*)d_in[3];
    const float* g1 = (const float*)d_in[4];
    const float* w2 = (const float*)d_in[5];
    const float* b2 = (const float*)d_in[6];
    const float* g2 = (const float*)d_in[7];
    const float* w3 = (const float*)d_in[8];
    const float* b3 = (const float*)d_in[9];
    const float* g3 = (const float*)d_in[10];
    const float* w4 = (const float*)d_in[11];
    const float* b4 = (const float*)d_in[12];
    const float* g4 = (const float*)d_in[13];
    const float* w5 = (const float*)d_in[14];
    const float* b5 = (const float*)d_in[15];
    const float* g5 = (const float*)d_in[16];
    const float* wh = (const float*)d_in[17];
    const float* bh = (const float*)d_in[18];
    const float* gh = (const float*)d_in[19];
    float* out = (float*)d_out;

    // workspace layout (float units; all 16B aligned)
    float* ws = (float*)d_ws;
    ushort_t* h1b = (ushort_t*)ws;                 // 28,311,552 u = 14,155,776 f
    ushort_t* h2b = (ushort_t*)(ws + 14155776);    //  7,077,888 u =  3,538,944 f
    ushort_t* h3b = (ushort_t*)(ws + 17694720);    //  7,077,888 u =  3,538,944 f
    ushort_t* h4b = (ushort_t*)(ws + 21233664);    //  1,769,472 u =    884,736 f
    float* h5 = ws + 22118400;                     //  1,769,472 f
    float* m2 = ws + 23887872;                     //    221,184 f
    float* m3 = ws + 24109056;                     //     27,648 f
    float* partials = ws + 24136704;               //      6,912 f
    ushort_t* wp1 = (ushort_t*)(ws + 24143616);    //     512 u =    256 f
    ushort_t* wp2 = (ushort_t*)(ws + 24143872);    //  14,336 u =  7,168 f
    ushort_t* wp3 = (ushort_t*)(ws + 24151040);    //  27,648 u = 13,824 f
    ushort_t* wp4 = (ushort_t*)(ws + 24164864);    //  55,296 u = 27,648 f
    ushort_t* wp5 = (ushort_t*)(ws + 24192512);    // 110,592 u = 55,296 f

    // prep: all weight packs + m1->m2 in one launch; then m2->m3
    prep_k<<<1678, 256, 0, stream>>>(w1, w2, w3, w4, w5, m1,
                                     wp1, wp2, wp3, wp4, wp5, m2);
    dmask_k<24, 48><<<108, 256, 0, stream>>>(m2, m3);

    // layer 1: MFMA tile conv + fused norm16
    conv1_mfma_k<<<27648, 256, 0, stream>>>(x, m1, wp1, b1, g1, h1b);
    // layer 2: MFMA (tap pairs, 32-voxel tiles) + fused norm
    conv2_mfma_k<<<1728, 256, 0, stream>>>(h1b, wp2, b2, g2, m2, h2b);
    // layer 3: MFMA (32-voxel tiles, full unroll) + fused norm
    conv3_mfma_k<<<1728, 256, 0, stream>>>(h2b, wp3, b3, g3, m2, h3b);
    // layer 4: MFMA (full unroll) + block-fused 64-ch norm -> bf16
    conv45_k<48, 32, 2, true><<<1728, 256, 0, stream>>>(h3b, wp4, b4, g4, m3, h4b, nullptr);
    // layer 5: MFMA (full unroll) + block-fused 64-ch norm -> fp32
    conv45_k<24, 64, 1, false><<<1728, 256, 0, stream>>>(h4b, wp5, b5, g5, m3, nullptr, h5);

    // pool + head
    pool1_k<<<108, 256, 0, stream>>>(h5, partials);
    pool2_head_k<<<1, 128, 0, stream>>>(partials, wh, bh, gh, out);
}

// Round 7
// 323.030 us; speedup vs baseline: 9.6230x; 1.0116x over previous
//
#include <hip/hip_runtime.h>
#include <math.h>

#define K_ADA 0.1f
#define NEPS 1e-5f

typedef __attribute__((ext_vector_type(8))) short short8;
typedef __attribute__((ext_vector_type(4))) float f32x4;
typedef unsigned short ushort_t;

__device__ __forceinline__ ushort_t f2b(float f) {
    union { float f; unsigned u; } v; v.f = f;
    unsigned r = (v.u + 0x7fffu + ((v.u >> 16) & 1u)) >> 16;
    return (ushort_t)r;
}

__device__ __forceinline__ float wave_sum64(float v) {
#pragma unroll
    for (int m = 1; m < 64; m <<= 1) v += __shfl_xor(v, m, 64);
    return v;
}

// ---- generic pack element: [3,3,3,CIN,COUT] fp32 -> B-fragment bf16 ----
template <int CIN, int COUT>
__device__ __forceinline__ void pack_w_el(const float* __restrict__ w,
                                          ushort_t* __restrict__ wp, int t)
{
    constexpr int NKH = CIN / 32;
    constexpr int NCT = COUT / 16;
    int jj = t & 7;
    int lane = (t >> 3) & 63;
    int rest = t >> 9;              // (tap*NCT + ct)*NKH + kh
    int kh = rest % NKH;
    int rest2 = rest / NKH;
    int ct = rest2 % NCT;
    int tap = rest2 / NCT;
    int cin = kh * 32 + (lane >> 4) * 8 + jj;
    int cout = ct * 16 + (lane & 15);
    wp[t] = f2b(w[(tap * CIN + cin) * COUT + cout]);
}

// ---- merged prep: pack w1..w5 + dmask m1->m2 + zero-pad block, one launch ----
__global__ __launch_bounds__(256) void prep_k(
    const float* __restrict__ w1, const float* __restrict__ w2,
    const float* __restrict__ w3, const float* __restrict__ w4,
    const float* __restrict__ w5, const float* __restrict__ m1,
    ushort_t* __restrict__ wp1, ushort_t* __restrict__ wp2,
    ushort_t* __restrict__ wp3, ushort_t* __restrict__ wp4,
    ushort_t* __restrict__ wp5, float* __restrict__ m2,
    float* __restrict__ zeropad)
{
    int t = blockIdx.x * 256 + threadIdx.x;
    if (t < 512) {
        // w1 [27][1][16] -> single frag, K=taps (pad 32)
        int jj = t & 7;
        int lane = t >> 3;
        int tap = (lane >> 4) * 8 + jj;
        int cout = lane & 15;
        wp1[t] = (tap < 27) ? f2b(w1[tap * 16 + cout]) : (ushort_t)0;
    } else if (t < 14848) {
        // w2 [27][16][32] -> tap-paired frags: 14 pairs x 2 ct
        int u = t - 512;
        int jj = u & 7;
        int lane = (u >> 3) & 63;
        int rest = u >> 9;
        int ct = rest & 1;
        int p = rest >> 1;
        int tap = 2 * p + (lane >> 5);
        int cin = ((lane >> 4) & 1) * 8 + jj;
        int cout = ct * 16 + (lane & 15);
        wp2[u] = (tap < 27) ? f2b(w2[(tap * 16 + cin) * 32 + cout]) : (ushort_t)0;
    } else if (t < 42496) {
        pack_w_el<32, 32>(w3, wp3, t - 14848);
    } else if (t < 97792) {
        pack_w_el<32, 64>(w4, wp4, t - 42496);
    } else if (t < 208384) {
        pack_w_el<64, 64>(w5, wp5, t - 97792);
    } else if (t < 429568) {
        // dmask 96 -> 48
        int v = t - 208384;
        constexpr int GO = 48, GI = 96;
        int b = v / (GO * GO * GO);
        int r = v % (GO * GO * GO);
        int d = r / (GO * GO), h = (r / GO) % GO, x = r % GO;
        float mx = 0.f;
        for (int kd = 0; kd < 3; ++kd) {
            int zd = 2 * d + kd - 1; if ((unsigned)zd >= GI) continue;
            for (int kh = 0; kh < 3; ++kh) {
                int zh = 2 * h + kh - 1; if ((unsigned)zh >= GI) continue;
                for (int kw = 0; kw < 3; ++kw) {
                    int zx = 2 * x + kw - 1; if ((unsigned)zx >= GI) continue;
                    mx = fmaxf(mx, m1[((b * GI + zd) * GI + zh) * GI + zx]);
                }
            }
        }
        m2[v] = mx;
    } else if (t < 429576) {
        zeropad[t - 429568] = 0.f;  // 32B zero block for OOB load redirection
    }
}

// downsample mask: max over 3^3 window, stride 2, pad 1 (m2 -> m3)
template <int GO, int GI>
__global__ __launch_bounds__(256) void dmask_k(const float* __restrict__ mi,
                                               float* __restrict__ mo)
{
    constexpr int N = 2 * GO * GO * GO;
    int v = blockIdx.x * 256 + threadIdx.x;
    if (v >= N) return;
    int b = v / (GO * GO * GO);
    int r = v % (GO * GO * GO);
    int d = r / (GO * GO), h = (r / GO) % GO, x = r % GO;
    float mx = 0.f;
    for (int kd = 0; kd < 3; ++kd) {
        int zd = 2 * d + kd - 1; if ((unsigned)zd >= GI) continue;
        for (int kh = 0; kh < 3; ++kh) {
            int zh = 2 * h + kh - 1; if ((unsigned)zh >= GI) continue;
            for (int kw = 0; kw < 3; ++kw) {
                int zx = 2 * x + kw - 1; if ((unsigned)zx >= GI) continue;
                mx = fmaxf(mx, mi[((b * GI + zd) * GI + zh) * GI + zx]);
            }
        }
    }
    mo[v] = mx;
}

// ---- layer 1 MFMA: 1->16, s=1. Wave = 16-voxel tile. K = 27 taps (pad 32). ----
// All loads unconditional: OOB lanes read the zero-pad block.
__global__ __launch_bounds__(256) void conv1_mfma_k(const float* __restrict__ x,
                                                    const float* __restrict__ m1,
                                                    const ushort_t* __restrict__ wp1,
                                                    const float* __restrict__ bias,
                                                    const float* __restrict__ gain,
                                                    const float* __restrict__ zerof,
                                                    ushort_t* __restrict__ h1b)
{
    constexpr int G = 96, G3 = G * G * G;
    int wave = (blockIdx.x * 256 + threadIdx.x) >> 6;
    int lane = threadIdx.x & 63;
    int m = lane & 15, q = lane >> 4;
    int vb = wave * 16;
    int vm = vb + m;
    int b = vm / G3;
    int rr = vm % G3;
    int dm = rr / (G * G), hm = (rr / G) % G, xm = rr % G;

    bool act = (m1[vm] != 0.f);
    if (!__any(act)) {
        reinterpret_cast<unsigned long long*>(h1b + (size_t)vb * 16)[lane] = 0ull;
        return;
    }

    float xs[8];
#pragma unroll
    for (int j = 0; j < 8; ++j) {
        int k = q * 8 + j;
        int kd = k / 9, kh = (k / 3) % 3, kw = k % 3;
        int id = dm + kd - 1, ih = hm + kh - 1, ix = xm + kw - 1;
        bool ok = (k < 27) && ((unsigned)id < (unsigned)G) &&
                  ((unsigned)ih < (unsigned)G) && ((unsigned)ix < (unsigned)G);
        const float* xp = ok ? (x + (((size_t)b * G + id) * G + ih) * G + ix) : zerof;
        xs[j] = *xp;
    }
    ushort_t av[8];
#pragma unroll
    for (int j = 0; j < 8; ++j) av[j] = f2b(xs[j]);
    short8 a = *reinterpret_cast<short8*>(av);
    short8 bfr = *reinterpret_cast<const short8*>(wp1 + lane * 8);
    f32x4 acc = {0.f, 0.f, 0.f, 0.f};
    acc = __builtin_amdgcn_mfma_f32_16x16x32_bf16(a, bfr, acc, 0, 0, 0);

    float bn = bias[m], gn = gain[m];
#pragma unroll
    for (int i = 0; i < 4; ++i) {
        int w = vb + q * 4 + i;
        float xv = acc[i] + bn;
        float s = xv;
#pragma unroll
        for (int mk = 1; mk < 16; mk <<= 1) s += __shfl_xor(s, mk, 64);
        float mean = s * (1.f / 16.f);
        float dd = xv - mean;
        float ss = dd * dd;
#pragma unroll
        for (int mk = 1; mk < 16; mk <<= 1) ss += __shfl_xor(ss, mk, 64);
        float rs = rsqrtf(ss * (1.f / 16.f) + NEPS);
        float xn = dd * rs;
        float o = fmaxf(gn * (1.f - K_ADA * xn) * xn, 0.f);
        h1b[(size_t)w * 16 + m] = (m1[w] != 0.f) ? f2b(o) : (ushort_t)0;
    }
}

// ---- fused 32-channel AdaNorm+ReLU epilogue (wave: 16 voxels x 32 couts) ----
__device__ __forceinline__ void norm32_epilogue(
    f32x4 acc0, f32x4 acc1, int vb, int q, int n,
    const float* __restrict__ bias, const float* __restrict__ gain,
    const float* __restrict__ mask, ushort_t* __restrict__ outb)
{
    float b0 = bias[n], b1 = bias[16 + n];
    float g0 = gain[n], g1 = gain[16 + n];
#pragma unroll
    for (int i = 0; i < 4; ++i) {
        int w = vb + q * 4 + i;
        float x0 = acc0[i] + b0;
        float x1 = acc1[i] + b1;
        float s = x0 + x1;
#pragma unroll
        for (int mk = 1; mk < 16; mk <<= 1) s += __shfl_xor(s, mk, 64);
        float mean = s * (1.f / 32.f);
        float d0 = x0 - mean, d1 = x1 - mean;
        float ss = d0 * d0 + d1 * d1;
#pragma unroll
        for (int mk = 1; mk < 16; mk <<= 1) ss += __shfl_xor(ss, mk, 64);
        float rs = rsqrtf(ss * (1.f / 32.f) + NEPS);
        float mv = mask[w];
        float xn0 = d0 * rs, xn1 = d1 * rs;
        float o0 = fmaxf(g0 * (1.f - K_ADA * xn0) * xn0, 0.f);
        float o1 = fmaxf(g1 * (1.f - K_ADA * xn1) * xn1, 0.f);
        if (mv == 0.f) { o0 = 0.f; o1 = 0.f; }
        outb[(size_t)w * 32 + n]      = f2b(o0);
        outb[(size_t)w * 32 + 16 + n] = f2b(o1);
    }
}

// ---- layer 2 MFMA: 16->32, s=2, K=32 = tap pair. Wave = 32 voxels x 32 couts ----
__global__ __launch_bounds__(256) void conv2_mfma_k(
    const ushort_t* __restrict__ h1b, const ushort_t* __restrict__ wp2,
    const float* __restrict__ bias, const float* __restrict__ gain,
    const float* __restrict__ m2, const ushort_t* __restrict__ zp,
    ushort_t* __restrict__ h2b)
{
    constexpr int G = 48, GI = 96, G3 = G * G * G;
    int wave = (blockIdx.x * 256 + threadIdx.x) >> 6;
    int lane = threadIdx.x & 63;
    int m = lane & 15, q = lane >> 4;
    int vb = wave * 32;
    int tq = q >> 1;   // tap within pair
    int hq = q & 1;    // cin half

    int vmA = vb + m, vmB = vb + 16 + m;
    int bA = vmA / G3, rA = vmA % G3;
    int dA = rA / (G * G), hA = (rA / G) % G, xA = rA % G;
    int bB = vmB / G3, rB = vmB % G3;
    int dB = rB / (G * G), hB = (rB / G) % G, xB = rB % G;

    f32x4 acc00 = {0.f, 0.f, 0.f, 0.f}, acc01 = acc00, acc10 = acc00, acc11 = acc00;
#pragma unroll
    for (int p = 0; p < 14; ++p) {
        int tap = 2 * p + tq;
        int kd = tap / 9, kh = (tap / 3) % 3, kw = tap % 3;
        int idA = 2 * dA + kd - 1, ihA = 2 * hA + kh - 1, ixA = 2 * xA + kw - 1;
        int idB = 2 * dB + kd - 1, ihB = 2 * hB + kh - 1, ixB = 2 * xB + kw - 1;
        bool okA = (tap < 27) && ((unsigned)idA < (unsigned)GI) &&
                   ((unsigned)ihA < (unsigned)GI) && ((unsigned)ixA < (unsigned)GI);
        bool okB = (tap < 27) && ((unsigned)idB < (unsigned)GI) &&
                   ((unsigned)ihB < (unsigned)GI) && ((unsigned)ixB < (unsigned)GI);
        size_t nvA = (((size_t)bA * GI + idA) * GI + ihA) * GI + ixA;
        size_t nvB = (((size_t)bB * GI + idB) * GI + ihB) * GI + ixB;
        const ushort_t* pA = okA ? (h1b + nvA * 16 + hq * 8) : zp;
        const ushort_t* pB = okB ? (h1b + nvB * 16 + hq * 8) : zp;
        short8 a0 = *reinterpret_cast<const short8*>(pA);
        short8 a1 = *reinterpret_cast<const short8*>(pB);
        short8 bv0 = *reinterpret_cast<const short8*>(wp2 + ((size_t)(p * 2 + 0) * 64 + lane) * 8);
        short8 bv1 = *reinterpret_cast<const short8*>(wp2 + ((size_t)(p * 2 + 1) * 64 + lane) * 8);
        acc00 = __builtin_amdgcn_mfma_f32_16x16x32_bf16(a0, bv0, acc00, 0, 0, 0);
        acc01 = __builtin_amdgcn_mfma_f32_16x16x32_bf16(a0, bv1, acc01, 0, 0, 0);
        acc10 = __builtin_amdgcn_mfma_f32_16x16x32_bf16(a1, bv0, acc10, 0, 0, 0);
        acc11 = __builtin_amdgcn_mfma_f32_16x16x32_bf16(a1, bv1, acc11, 0, 0, 0);
    }
    norm32_epilogue(acc00, acc01, vb,      q, m, bias, gain, m2, h2b);
    norm32_epilogue(acc10, acc11, vb + 16, q, m, bias, gain, m2, h2b);
}

// ---- layer 3 MFMA: 32->32, s=1, full unroll, unconditional loads ----
__global__ __launch_bounds__(256, 4) void conv3_mfma_k(
    const ushort_t* __restrict__ h2b, const ushort_t* __restrict__ wp3,
    const float* __restrict__ bias, const float* __restrict__ gain,
    const float* __restrict__ m2, const ushort_t* __restrict__ zp,
    ushort_t* __restrict__ h3b)
{
    constexpr int G = 48, G3 = G * G * G;
    int wave = (blockIdx.x * 256 + threadIdx.x) >> 6;
    int lane = threadIdx.x & 63;
    int m = lane & 15, q = lane >> 4;
    int vb = wave * 32;

    int vmA = vb + m, vmB = vb + 16 + m;
    int bA = vmA / G3, rA = vmA % G3;
    int dA = rA / (G * G), hA = (rA / G) % G, xA = rA % G;
    int bB = vmB / G3, rB = vmB % G3;
    int dB = rB / (G * G), hB = (rB / G) % G, xB = rB % G;

    f32x4 acc00 = {0.f, 0.f, 0.f, 0.f}, acc01 = acc00, acc10 = acc00, acc11 = acc00;
#pragma unroll
    for (int tap = 0; tap < 27; ++tap) {
        const int kd = tap / 9, kh = (tap / 3) % 3, kw = tap % 3;
        int idA = dA + kd - 1, ihA = hA + kh - 1, ixA = xA + kw - 1;
        int idB = dB + kd - 1, ihB = hB + kh - 1, ixB = xB + kw - 1;
        bool okA = ((unsigned)idA < (unsigned)G) && ((unsigned)ihA < (unsigned)G) &&
                   ((unsigned)ixA < (unsigned)G);
        bool okB = ((unsigned)idB < (unsigned)G) && ((unsigned)ihB < (unsigned)G) &&
                   ((unsigned)ixB < (unsigned)G);
        size_t nvA = (((size_t)bA * G + idA) * G + ihA) * G + ixA;
        size_t nvB = (((size_t)bB * G + idB) * G + ihB) * G + ixB;
        const ushort_t* pA = okA ? (h2b + nvA * 32 + q * 8) : zp;
        const ushort_t* pB = okB ? (h2b + nvB * 32 + q * 8) : zp;
        short8 a0 = *reinterpret_cast<const short8*>(pA);
        short8 a1 = *reinterpret_cast<const short8*>(pB);
        short8 bv0 = *reinterpret_cast<const short8*>(wp3 + ((size_t)(tap * 2 + 0) * 64 + lane) * 8);
        short8 bv1 = *reinterpret_cast<const short8*>(wp3 + ((size_t)(tap * 2 + 1) * 64 + lane) * 8);
        acc00 = __builtin_amdgcn_mfma_f32_16x16x32_bf16(a0, bv0, acc00, 0, 0, 0);
        acc01 = __builtin_amdgcn_mfma_f32_16x16x32_bf16(a0, bv1, acc01, 0, 0, 0);
        acc10 = __builtin_amdgcn_mfma_f32_16x16x32_bf16(a1, bv0, acc10, 0, 0, 0);
        acc11 = __builtin_amdgcn_mfma_f32_16x16x32_bf16(a1, bv1, acc11, 0, 0, 0);
    }
    norm32_epilogue(acc00, acc01, vb,      q, m, bias, gain, m2, h3b);
    norm32_epilogue(acc10, acc11, vb + 16, q, m, bias, gain, m2, h3b);
}

// ---- layers 4/5: block = 4 ct-waves of one 16-voxel tile ----
// Staged in groups of 9: 9 A + 9 B unconditional loads, then 9 MFMAs.
template <int G_IN, int CIN, int STRIDE, bool OUTB>
__global__ __launch_bounds__(256, 4) void conv45_k(const ushort_t* __restrict__ Ab,
                                                   const ushort_t* __restrict__ Wp,
                                                   const float* __restrict__ bias,
                                                   const float* __restrict__ gain,
                                                   const float* __restrict__ mask,
                                                   const ushort_t* __restrict__ zp,
                                                   ushort_t* __restrict__ outb,
                                                   float* __restrict__ outf)
{
    constexpr int G = 24, G3 = G * G * G;
    constexpr int NKH = CIN / 32;
    constexpr int NT = 27 * NKH;
    int ct = threadIdx.x >> 6;
    int lane = threadIdx.x & 63;
    int m = lane & 15, q = lane >> 4;
    int vb = blockIdx.x * 16;
    int vm = vb + m;
    int b = vm / G3;
    int rr = vm % G3;
    int dm = rr / (G * G), hm = (rr / G) % G, xm = rr % G;

    f32x4 acc = {0.f, 0.f, 0.f, 0.f};
#pragma unroll
    for (int g = 0; g < NT / 9; ++g) {
        short8 abuf[9], bbuf[9];
#pragma unroll
        for (int j = 0; j < 9; ++j) {
            int it = g * 9 + j;
            int tap = it / NKH, k2 = it % NKH;
            const int kd = tap / 9, kh = (tap / 3) % 3, kw = tap % 3;
            int id = dm * STRIDE + kd - 1;
            int ih = hm * STRIDE + kh - 1;
            int ix = xm * STRIDE + kw - 1;
            bool ok = ((unsigned)id < (unsigned)G_IN) &&
                      ((unsigned)ih < (unsigned)G_IN) &&
                      ((unsigned)ix < (unsigned)G_IN);
            size_t nv = (((size_t)b * G_IN + id) * G_IN + ih) * G_IN + ix;
            const ushort_t* pA = ok ? (Ab + nv * CIN + k2 * 32 + q * 8) : zp;
            abuf[j] = *reinterpret_cast<const short8*>(pA);
            bbuf[j] = *reinterpret_cast<const short8*>(
                Wp + (((size_t)(tap * 4 + ct) * NKH + k2) * 64 + lane) * 8);
        }
#pragma unroll
        for (int j = 0; j < 9; ++j)
            acc = __builtin_amdgcn_mfma_f32_16x16x32_bf16(abuf[j], bbuf[j], acc, 0, 0, 0);
    }

    __shared__ float lds[16][65];
    float bn = bias[ct * 16 + m];
#pragma unroll
    for (int i = 0; i < 4; ++i) lds[q * 4 + i][ct * 16 + m] = acc[i] + bn;
    __syncthreads();

    float gn = gain[lane];
#pragma unroll
    for (int i = 0; i < 4; ++i) {
        int vloc = ct * 4 + i;
        int w = vb + vloc;
        float val = lds[vloc][lane];
        float mean = wave_sum64(val) * (1.f / 64.f);
        float dd = val - mean;
        float var = wave_sum64(dd * dd) * (1.f / 64.f) + NEPS;
        float xn = dd * rsqrtf(var);
        float o = fmaxf(gn * (1.f - K_ADA * xn) * xn, 0.f);
        if (mask[w] == 0.f) o = 0.f;
        if (OUTB) outb[(size_t)w * 64 + lane] = f2b(o);
        else      outf[(size_t)w * 64 + lane] = o;
    }
}

// ---- Global max pool stage 1 (h5 >= 0 with zeros at inactive -> plain max) ----
__global__ __launch_bounds__(256) void pool1_k(const float* __restrict__ h5,
                                               float* __restrict__ partials)
{
    int chunk = blockIdx.x % 54;
    int b = blockIdx.x / 54;
    int c = threadIdx.x & 63;
    int s = threadIdx.x >> 6;
    const float* base = h5 + ((size_t)b * 13824 + chunk * 256) * 64;
    float mx = 0.f;
#pragma unroll 4
    for (int v = s; v < 256; v += 4) mx = fmaxf(mx, base[v * 64 + c]);
    __shared__ float red[256];
    red[threadIdx.x] = mx;
    __syncthreads();
    if (s == 0)
        partials[blockIdx.x * 64 + c] =
            fmaxf(fmaxf(red[c], red[64 + c]), fmaxf(red[128 + c], red[192 + c]));
}

// ---- stage 2 + head ----
__global__ __launch_bounds__(128) void pool2_head_k(const float* __restrict__ partials,
                                                    const float* __restrict__ wh,
                                                    const float* __restrict__ bh,
                                                    const float* __restrict__ gh,
                                                    float* __restrict__ out)
{
    __shared__ float pooled[2][64];
    int t = threadIdx.x;
    int b = t >> 6;
    int f = t & 63;
    float mx = 0.f;
    for (int p = 0; p < 54; ++p) mx = fmaxf(mx, partials[(b * 54 + p) * 64 + f]);
    pooled[b][f] = mx;
    __syncthreads();
    float acc = bh[f];
#pragma unroll
    for (int k = 0; k < 64; ++k) acc += pooled[b][k] * wh[k * 64 + f];
    float mean = wave_sum64(acc) * (1.f / 64.f);
    float dd = acc - mean;
    float var = wave_sum64(dd * dd) * (1.f / 64.f) + NEPS;
    float xn = dd * rsqrtf(var);
    float val = gh[f] * (1.f - K_ADA * xn) * xn;
    out[t] = fmaxf(val, 0.f);
}

extern "C" void kernel_launch(void* const* d_in, const int* in_sizes, int n_in,
                              void* d_out, int out_size, void* d_ws, size_t ws_size,
                              hipStream_t stream)
{
    const float* x  = (const float*)d_in[0];
    const float* m1 = (const float*)d_in[1];
    const float* w1 = (const float*)d_in[2];
    const float* b1 = (const float*)d_in[3];
    const float* g1 = (const float*)d_in[4];
    const float* w2 = (const float*)d_in[5];
    const float* b2 = (const float*)d_in[6];
    const float* g2 = (const float*)d_in[7];
    const float* w3 = (const float*)d_in[8];
    const float* b3 = (const float*)d_in[9];
    const float* g3 = (const float*)d_in[10];
    const float* w4 = (const float*)d_in[11];
    const float* b4 = (const float*)d_in[12];
    const float* g4 = (const float*)d_in[13];
    const float* w5 = (const float*)d_in[14];
    const float* b5 = (const float*)d_in[15];
    const float* g5 = (const float*)d_in[16];
    const float* wh = (const float*)d_in[17];
    const float* bh = (const float*)d_in[18];
    const float* gh = (const float*)d_in[19];
    float* out = (float*)d_out;

    // workspace layout (float units; all 16B aligned)
    float* ws = (float*)d_ws;
    ushort_t* h1b = (ushort_t*)ws;                 // 28,311,552 u = 14,155,776 f
    ushort_t* h2b = (ushort_t*)(ws + 14155776);    //  7,077,888 u =  3,538,944 f
    ushort_t* h3b = (ushort_t*)(ws + 17694720);    //  7,077,888 u =  3,538,944 f
    ushort_t* h4b = (ushort_t*)(ws + 21233664);    //  1,769,472 u =    884,736 f
    float* h5 = ws + 22118400;                     //  1,769,472 f
    float* m2 = ws + 23887872;                     //    221,184 f
    float* m3 = ws + 24109056;                     //     27,648 f
    float* partials = ws + 24136704;               //      6,912 f
    ushort_t* wp1 = (ushort_t*)(ws + 24143616);    //     512 u =    256 f
    ushort_t* wp2 = (ushort_t*)(ws + 24143872);    //  14,336 u =  7,168 f
    ushort_t* wp3 = (ushort_t*)(ws + 24151040);    //  27,648 u = 13,824 f
    ushort_t* wp4 = (ushort_t*)(ws + 24164864);    //  55,296 u = 27,648 f
    ushort_t* wp5 = (ushort_t*)(ws + 24192512);    // 110,592 u = 55,296 f
    float* zeropad = ws + 24247808;                //          8 f (32B zero block)

    // prep: weight packs + m1->m2 + zero-pad, one launch; then m2->m3
    prep_k<<<1679, 256, 0, stream>>>(w1, w2, w3, w4, w5, m1,
                                     wp1, wp2, wp3, wp4, wp5, m2, zeropad);
    dmask_k<24, 48><<<108, 256, 0, stream>>>(m2, m3);

    const ushort_t* zp = (const ushort_t*)zeropad;
    // layer 1: MFMA tile conv + fused norm16
    conv1_mfma_k<<<27648, 256, 0, stream>>>(x, m1, wp1, b1, g1, zeropad, h1b);
    // layer 2: MFMA (tap pairs, 32-voxel tiles) + fused norm
    conv2_mfma_k<<<1728, 256, 0, stream>>>(h1b, wp2, b2, g2, m2, zp, h2b);
    // layer 3: MFMA (32-voxel tiles, full unroll) + fused norm
    conv3_mfma_k<<<1728, 256, 0, stream>>>(h2b, wp3, b3, g3, m2, zp, h3b);
    // layer 4: MFMA (staged loads) + block-fused 64-ch norm -> bf16
    conv45_k<48, 32, 2, true><<<1728, 256, 0, stream>>>(h3b, wp4, b4, g4, m3, zp, h4b, nullptr);
    // layer 5: MFMA (staged loads) + block-fused 64-ch norm -> fp32
    conv45_k<24, 64, 1, false><<<1728, 256, 0, stream>>>(h4b, wp5, b5, g5, m3, zp, nullptr, h5);

    // pool + head
    pool1_k<<<108, 256, 0, stream>>>(h5, partials);
    pool2_head_k<<<1, 128, 0, stream>>>(partials, wh, bh, gh, out);
}

// Round 8
// 270.557 us; speedup vs baseline: 11.4893x; 1.1939x over previous
//
#include <hip/hip_runtime.h>
#include <math.h>

#define K_ADA 0.1f
#define NEPS 1e-5f

typedef __attribute__((ext_vector_type(8))) short short8;
typedef __attribute__((ext_vector_type(4))) float f32x4;
typedef unsigned short ushort_t;

__device__ __forceinline__ ushort_t f2b(float f) {
    union { float f; unsigned u; } v; v.f = f;
    unsigned r = (v.u + 0x7fffu + ((v.u >> 16) & 1u)) >> 16;
    return (ushort_t)r;
}

__device__ __forceinline__ float wave_sum64(float v) {
#pragma unroll
    for (int m = 1; m < 64; m <<= 1) v += __shfl_xor(v, m, 64);
    return v;
}

// ---- generic pack element: [3,3,3,CIN,COUT] fp32 -> B-fragment bf16 ----
template <int CIN, int COUT>
__device__ __forceinline__ void pack_w_el(const float* __restrict__ w,
                                          ushort_t* __restrict__ wp, int t)
{
    constexpr int NKH = CIN / 32;
    constexpr int NCT = COUT / 16;
    int jj = t & 7;
    int lane = (t >> 3) & 63;
    int rest = t >> 9;              // (tap*NCT + ct)*NKH + kh
    int kh = rest % NKH;
    int rest2 = rest / NKH;
    int ct = rest2 % NCT;
    int tap = rest2 / NCT;
    int cin = kh * 32 + (lane >> 4) * 8 + jj;
    int cout = ct * 16 + (lane & 15);
    wp[t] = f2b(w[(tap * CIN + cin) * COUT + cout]);
}

// ---- merged prep: pack w1..w5 + dmask m1->m2 + zero-pad block, one launch ----
__global__ __launch_bounds__(256) void prep_k(
    const float* __restrict__ w1, const float* __restrict__ w2,
    const float* __restrict__ w3, const float* __restrict__ w4,
    const float* __restrict__ w5, const float* __restrict__ m1,
    ushort_t* __restrict__ wp1, ushort_t* __restrict__ wp2,
    ushort_t* __restrict__ wp3, ushort_t* __restrict__ wp4,
    ushort_t* __restrict__ wp5, float* __restrict__ m2,
    float* __restrict__ zeropad)
{
    int t = blockIdx.x * 256 + threadIdx.x;
    if (t < 512) {
        // w1 [27][1][16] -> single frag, K=taps (pad 32)
        int jj = t & 7;
        int lane = t >> 3;
        int tap = (lane >> 4) * 8 + jj;
        int cout = lane & 15;
        wp1[t] = (tap < 27) ? f2b(w1[tap * 16 + cout]) : (ushort_t)0;
    } else if (t < 14848) {
        // w2 [27][16][32] -> tap-paired frags: 14 pairs x 2 ct
        int u = t - 512;
        int jj = u & 7;
        int lane = (u >> 3) & 63;
        int rest = u >> 9;
        int ct = rest & 1;
        int p = rest >> 1;
        int tap = 2 * p + (lane >> 5);
        int cin = ((lane >> 4) & 1) * 8 + jj;
        int cout = ct * 16 + (lane & 15);
        wp2[u] = (tap < 27) ? f2b(w2[(tap * 16 + cin) * 32 + cout]) : (ushort_t)0;
    } else if (t < 42496) {
        pack_w_el<32, 32>(w3, wp3, t - 14848);
    } else if (t < 97792) {
        pack_w_el<32, 64>(w4, wp4, t - 42496);
    } else if (t < 208384) {
        pack_w_el<64, 64>(w5, wp5, t - 97792);
    } else if (t < 429568) {
        // dmask 96 -> 48
        int v = t - 208384;
        constexpr int GO = 48, GI = 96;
        int b = v / (GO * GO * GO);
        int r = v % (GO * GO * GO);
        int d = r / (GO * GO), h = (r / GO) % GO, x = r % GO;
        float mx = 0.f;
        for (int kd = 0; kd < 3; ++kd) {
            int zd = 2 * d + kd - 1; if ((unsigned)zd >= GI) continue;
            for (int kh = 0; kh < 3; ++kh) {
                int zh = 2 * h + kh - 1; if ((unsigned)zh >= GI) continue;
                for (int kw = 0; kw < 3; ++kw) {
                    int zx = 2 * x + kw - 1; if ((unsigned)zx >= GI) continue;
                    mx = fmaxf(mx, m1[((b * GI + zd) * GI + zh) * GI + zx]);
                }
            }
        }
        m2[v] = mx;
    } else if (t < 429576) {
        zeropad[t - 429568] = 0.f;  // 32B zero block for OOB load redirection
    }
}

// downsample mask: max over 3^3 window, stride 2, pad 1 (m2 -> m3)
template <int GO, int GI>
__global__ __launch_bounds__(256) void dmask_k(const float* __restrict__ mi,
                                               float* __restrict__ mo)
{
    constexpr int N = 2 * GO * GO * GO;
    int v = blockIdx.x * 256 + threadIdx.x;
    if (v >= N) return;
    int b = v / (GO * GO * GO);
    int r = v % (GO * GO * GO);
    int d = r / (GO * GO), h = (r / GO) % GO, x = r % GO;
    float mx = 0.f;
    for (int kd = 0; kd < 3; ++kd) {
        int zd = 2 * d + kd - 1; if ((unsigned)zd >= GI) continue;
        for (int kh = 0; kh < 3; ++kh) {
            int zh = 2 * h + kh - 1; if ((unsigned)zh >= GI) continue;
            for (int kw = 0; kw < 3; ++kw) {
                int zx = 2 * x + kw - 1; if ((unsigned)zx >= GI) continue;
                mx = fmaxf(mx, mi[((b * GI + zd) * GI + zh) * GI + zx]);
            }
        }
    }
    mo[v] = mx;
}

// ---- layer 1 MFMA: 1->16, s=1. Wave = 16-voxel tile. K = 27 taps (pad 32). ----
__global__ __launch_bounds__(256) void conv1_mfma_k(const float* __restrict__ x,
                                                    const float* __restrict__ m1,
                                                    const ushort_t* __restrict__ wp1,
                                                    const float* __restrict__ bias,
                                                    const float* __restrict__ gain,
                                                    const float* __restrict__ zerof,
                                                    ushort_t* __restrict__ h1b)
{
    constexpr int G = 96, G3 = G * G * G;
    int wave = (blockIdx.x * 256 + threadIdx.x) >> 6;
    int lane = threadIdx.x & 63;
    int m = lane & 15, q = lane >> 4;
    int vb = wave * 16;
    int vm = vb + m;
    int b = vm / G3;
    int rr = vm % G3;
    int dm = rr / (G * G), hm = (rr / G) % G, xm = rr % G;

    bool act = (m1[vm] != 0.f);
    if (!__any(act)) {
        reinterpret_cast<unsigned long long*>(h1b + (size_t)vb * 16)[lane] = 0ull;
        return;
    }

    float xs[8];
#pragma unroll
    for (int j = 0; j < 8; ++j) {
        int k = q * 8 + j;
        int kd = k / 9, kh = (k / 3) % 3, kw = k % 3;
        int id = dm + kd - 1, ih = hm + kh - 1, ix = xm + kw - 1;
        bool ok = (k < 27) && ((unsigned)id < (unsigned)G) &&
                  ((unsigned)ih < (unsigned)G) && ((unsigned)ix < (unsigned)G);
        const float* xp = ok ? (x + (((size_t)b * G + id) * G + ih) * G + ix) : zerof;
        xs[j] = *xp;
    }
    ushort_t av[8];
#pragma unroll
    for (int j = 0; j < 8; ++j) av[j] = f2b(xs[j]);
    short8 a = *reinterpret_cast<short8*>(av);
    short8 bfr = *reinterpret_cast<const short8*>(wp1 + lane * 8);
    f32x4 acc = {0.f, 0.f, 0.f, 0.f};
    acc = __builtin_amdgcn_mfma_f32_16x16x32_bf16(a, bfr, acc, 0, 0, 0);

    float bn = bias[m], gn = gain[m];
#pragma unroll
    for (int i = 0; i < 4; ++i) {
        int w = vb + q * 4 + i;
        float xv = acc[i] + bn;
        float s = xv;
#pragma unroll
        for (int mk = 1; mk < 16; mk <<= 1) s += __shfl_xor(s, mk, 64);
        float mean = s * (1.f / 16.f);
        float dd = xv - mean;
        float ss = dd * dd;
#pragma unroll
        for (int mk = 1; mk < 16; mk <<= 1) ss += __shfl_xor(ss, mk, 64);
        float rs = rsqrtf(ss * (1.f / 16.f) + NEPS);
        float xn = dd * rs;
        float o = fmaxf(gn * (1.f - K_ADA * xn) * xn, 0.f);
        h1b[(size_t)w * 16 + m] = (m1[w] != 0.f) ? f2b(o) : (ushort_t)0;
    }
}

// ---- fused 32-channel AdaNorm+ReLU epilogue (wave: 16 voxels x 32 couts) ----
__device__ __forceinline__ void norm32_epilogue(
    f32x4 acc0, f32x4 acc1, int vb, int q, int n,
    const float* __restrict__ bias, const float* __restrict__ gain,
    const float* __restrict__ mask, ushort_t* __restrict__ outb)
{
    float b0 = bias[n], b1 = bias[16 + n];
    float g0 = gain[n], g1 = gain[16 + n];
#pragma unroll
    for (int i = 0; i < 4; ++i) {
        int w = vb + q * 4 + i;
        float x0 = acc0[i] + b0;
        float x1 = acc1[i] + b1;
        float s = x0 + x1;
#pragma unroll
        for (int mk = 1; mk < 16; mk <<= 1) s += __shfl_xor(s, mk, 64);
        float mean = s * (1.f / 32.f);
        float d0 = x0 - mean, d1 = x1 - mean;
        float ss = d0 * d0 + d1 * d1;
#pragma unroll
        for (int mk = 1; mk < 16; mk <<= 1) ss += __shfl_xor(ss, mk, 64);
        float rs = rsqrtf(ss * (1.f / 32.f) + NEPS);
        float mv = mask[w];
        float xn0 = d0 * rs, xn1 = d1 * rs;
        float o0 = fmaxf(g0 * (1.f - K_ADA * xn0) * xn0, 0.f);
        float o1 = fmaxf(g1 * (1.f - K_ADA * xn1) * xn1, 0.f);
        if (mv == 0.f) { o0 = 0.f; o1 = 0.f; }
        outb[(size_t)w * 32 + n]      = f2b(o0);
        outb[(size_t)w * 32 + 16 + n] = f2b(o1);
    }
}

// ---- layer 2 MFMA: 16->32, s=2, K=32 = tap pair. Wave = 32 voxels x 32 couts ----
__global__ __launch_bounds__(256) void conv2_mfma_k(
    const ushort_t* __restrict__ h1b, const ushort_t* __restrict__ wp2,
    const float* __restrict__ bias, const float* __restrict__ gain,
    const float* __restrict__ m2, const ushort_t* __restrict__ zp,
    ushort_t* __restrict__ h2b)
{
    constexpr int G = 48, GI = 96, G3 = G * G * G;
    int wave = (blockIdx.x * 256 + threadIdx.x) >> 6;
    int lane = threadIdx.x & 63;
    int m = lane & 15, q = lane >> 4;
    int vb = wave * 32;
    int tq = q >> 1;   // tap within pair
    int hq = q & 1;    // cin half

    int vmA = vb + m, vmB = vb + 16 + m;
    int bA = vmA / G3, rA = vmA % G3;
    int dA = rA / (G * G), hA = (rA / G) % G, xA = rA % G;
    int bB = vmB / G3, rB = vmB % G3;
    int dB = rB / (G * G), hB = (rB / G) % G, xB = rB % G;

    f32x4 acc00 = {0.f, 0.f, 0.f, 0.f}, acc01 = acc00, acc10 = acc00, acc11 = acc00;
#pragma unroll
    for (int p = 0; p < 14; ++p) {
        int tap = 2 * p + tq;
        int kd = tap / 9, kh = (tap / 3) % 3, kw = tap % 3;
        int idA = 2 * dA + kd - 1, ihA = 2 * hA + kh - 1, ixA = 2 * xA + kw - 1;
        int idB = 2 * dB + kd - 1, ihB = 2 * hB + kh - 1, ixB = 2 * xB + kw - 1;
        bool okA = (tap < 27) && ((unsigned)idA < (unsigned)GI) &&
                   ((unsigned)ihA < (unsigned)GI) && ((unsigned)ixA < (unsigned)GI);
        bool okB = (tap < 27) && ((unsigned)idB < (unsigned)GI) &&
                   ((unsigned)ihB < (unsigned)GI) && ((unsigned)ixB < (unsigned)GI);
        size_t nvA = (((size_t)bA * GI + idA) * GI + ihA) * GI + ixA;
        size_t nvB = (((size_t)bB * GI + idB) * GI + ihB) * GI + ixB;
        const ushort_t* pA = okA ? (h1b + nvA * 16 + hq * 8) : zp;
        const ushort_t* pB = okB ? (h1b + nvB * 16 + hq * 8) : zp;
        short8 a0 = *reinterpret_cast<const short8*>(pA);
        short8 a1 = *reinterpret_cast<const short8*>(pB);
        short8 bv0 = *reinterpret_cast<const short8*>(wp2 + ((size_t)(p * 2 + 0) * 64 + lane) * 8);
        short8 bv1 = *reinterpret_cast<const short8*>(wp2 + ((size_t)(p * 2 + 1) * 64 + lane) * 8);
        acc00 = __builtin_amdgcn_mfma_f32_16x16x32_bf16(a0, bv0, acc00, 0, 0, 0);
        acc01 = __builtin_amdgcn_mfma_f32_16x16x32_bf16(a0, bv1, acc01, 0, 0, 0);
        acc10 = __builtin_amdgcn_mfma_f32_16x16x32_bf16(a1, bv0, acc10, 0, 0, 0);
        acc11 = __builtin_amdgcn_mfma_f32_16x16x32_bf16(a1, bv1, acc11, 0, 0, 0);
    }
    norm32_epilogue(acc00, acc01, vb,      q, m, bias, gain, m2, h2b);
    norm32_epilogue(acc10, acc11, vb + 16, q, m, bias, gain, m2, h2b);
}

// ---- layer 3 MFMA: 32->32, s=1, full unroll, unconditional loads ----
__global__ __launch_bounds__(256, 4) void conv3_mfma_k(
    const ushort_t* __restrict__ h2b, const ushort_t* __restrict__ wp3,
    const float* __restrict__ bias, const float* __restrict__ gain,
    const float* __restrict__ m2, const ushort_t* __restrict__ zp,
    ushort_t* __restrict__ h3b)
{
    constexpr int G = 48, G3 = G * G * G;
    int wave = (blockIdx.x * 256 + threadIdx.x) >> 6;
    int lane = threadIdx.x & 63;
    int m = lane & 15, q = lane >> 4;
    int vb = wave * 32;

    int vmA = vb + m, vmB = vb + 16 + m;
    int bA = vmA / G3, rA = vmA % G3;
    int dA = rA / (G * G), hA = (rA / G) % G, xA = rA % G;
    int bB = vmB / G3, rB = vmB % G3;
    int dB = rB / (G * G), hB = (rB / G) % G, xB = rB % G;

    f32x4 acc00 = {0.f, 0.f, 0.f, 0.f}, acc01 = acc00, acc10 = acc00, acc11 = acc00;
#pragma unroll
    for (int tap = 0; tap < 27; ++tap) {
        const int kd = tap / 9, kh = (tap / 3) % 3, kw = tap % 3;
        int idA = dA + kd - 1, ihA = hA + kh - 1, ixA = xA + kw - 1;
        int idB = dB + kd - 1, ihB = hB + kh - 1, ixB = xB + kw - 1;
        bool okA = ((unsigned)idA < (unsigned)G) && ((unsigned)ihA < (unsigned)G) &&
                   ((unsigned)ixA < (unsigned)G);
        bool okB = ((unsigned)idB < (unsigned)G) && ((unsigned)ihB < (unsigned)G) &&
                   ((unsigned)ixB < (unsigned)G);
        size_t nvA = (((size_t)bA * G + idA) * G + ihA) * G + ixA;
        size_t nvB = (((size_t)bB * G + idB) * G + ihB) * G + ixB;
        const ushort_t* pA = okA ? (h2b + nvA * 32 + q * 8) : zp;
        const ushort_t* pB = okB ? (h2b + nvB * 32 + q * 8) : zp;
        short8 a0 = *reinterpret_cast<const short8*>(pA);
        short8 a1 = *reinterpret_cast<const short8*>(pB);
        short8 bv0 = *reinterpret_cast<const short8*>(wp3 + ((size_t)(tap * 2 + 0) * 64 + lane) * 8);
        short8 bv1 = *reinterpret_cast<const short8*>(wp3 + ((size_t)(tap * 2 + 1) * 64 + lane) * 8);
        acc00 = __builtin_amdgcn_mfma_f32_16x16x32_bf16(a0, bv0, acc00, 0, 0, 0);
        acc01 = __builtin_amdgcn_mfma_f32_16x16x32_bf16(a0, bv1, acc01, 0, 0, 0);
        acc10 = __builtin_amdgcn_mfma_f32_16x16x32_bf16(a1, bv0, acc10, 0, 0, 0);
        acc11 = __builtin_amdgcn_mfma_f32_16x16x32_bf16(a1, bv1, acc11, 0, 0, 0);
    }
    norm32_epilogue(acc00, acc01, vb,      q, m, bias, gain, m2, h3b);
    norm32_epilogue(acc10, acc11, vb + 16, q, m, bias, gain, m2, h3b);
}

// ---- layers 4/5: HALO-TILE implicit GEMM ----
// Block = 2x2x4 output tile (16 voxels) x 4 ct-waves. Input halo staged ONCE
// into LDS (coalesced, fully parallel); MFMA loop reads A from LDS and B
// (L2-hot packed weights) in register-staged groups of 9.
template <int G_IN, int CIN, int STRIDE, bool OUTB>
__global__ __launch_bounds__(256, 4) void conv45_tile_k(
    const ushort_t* __restrict__ Ab, const ushort_t* __restrict__ Wp,
    const float* __restrict__ bias, const float* __restrict__ gain,
    const float* __restrict__ mask,
    ushort_t* __restrict__ outb, float* __restrict__ outf)
{
    constexpr int G = 24;
    constexpr int NKH = CIN / 32;            // MFMAs per tap
    constexpr int NCH = CIN / 8;             // 16B chunks per voxel
    constexpr int PADC = NCH + 1;            // +1 chunk pad vs bank aliasing
    constexpr int HD = STRIDE + 3;           // halo dims for 2x2x4 tile
    constexpr int HH = STRIDE + 3;
    constexpr int HX = 3 * STRIDE + 3;
    constexpr int NHV = HD * HH * HX;        // 225 (s2) / 96 (s1)
    constexpr int NCHUNK = NHV * NCH;

    __shared__ __align__(16) ushort_t halo[NHV * PADC * 8];
    __shared__ float nbuf[16][65];

    int bid = blockIdx.x;
    int b = bid / 864;
    int r = bid % 864;
    int td = r / 72, th = (r / 6) % 12, tx = r % 6;
    int d0 = 2 * td, h0 = 2 * th, x0 = 4 * tx;
    int bd = d0 * STRIDE - 1, bh = h0 * STRIDE - 1, bx = x0 * STRIDE - 1;

    // ---- stage halo into LDS (zeros at OOB; exact) ----
    for (int c = threadIdx.x; c < NCHUNK; c += 256) {
        int hv = c / NCH, j = c % NCH;
        int gd = bd + hv / (HH * HX);
        int gh = bh + (hv / HX) % HH;
        int gx = bx + hv % HX;
        short8 val = {0, 0, 0, 0, 0, 0, 0, 0};
        if ((unsigned)gd < (unsigned)G_IN && (unsigned)gh < (unsigned)G_IN &&
            (unsigned)gx < (unsigned)G_IN)
            val = *reinterpret_cast<const short8*>(
                Ab + ((((size_t)b * G_IN + gd) * G_IN + gh) * G_IN + gx) * CIN + j * 8);
        *reinterpret_cast<short8*>(halo + ((size_t)hv * PADC + j) * 8) = val;
    }
    __syncthreads();

    int ct = threadIdx.x >> 6;
    int lane = threadIdx.x & 63;
    int m = lane & 15, q = lane >> 4;
    int md = (m >> 3) & 1, mh = (m >> 2) & 1, mx = m & 3;

    f32x4 acc = {0.f, 0.f, 0.f, 0.f};
    constexpr int NT = 27 * NKH;
    constexpr int GSZ = 9;
#pragma unroll
    for (int g = 0; g < NT / GSZ; ++g) {
        short8 ab[GSZ], bb[GSZ];
#pragma unroll
        for (int j = 0; j < GSZ; ++j) {
            int it = g * GSZ + j;
            int tap = it / NKH, k2 = it % NKH;
            const int kd = tap / 9, kh = (tap / 3) % 3, kw = tap % 3;
            int hv = ((md * STRIDE + kd) * HH + (mh * STRIDE + kh)) * HX +
                     (mx * STRIDE + kw);
            ab[j] = *reinterpret_cast<const short8*>(
                halo + ((size_t)hv * PADC + k2 * 4 + q) * 8);
            bb[j] = *reinterpret_cast<const short8*>(
                Wp + (((size_t)(tap * 4 + ct) * NKH + k2) * 64 + lane) * 8);
        }
#pragma unroll
        for (int j = 0; j < GSZ; ++j)
            acc = __builtin_amdgcn_mfma_f32_16x16x32_bf16(ab[j], bb[j], acc, 0, 0, 0);
    }

    // ---- fused 64-channel AdaNorm+ReLU ----
    float bn = bias[ct * 16 + m];
#pragma unroll
    for (int i = 0; i < 4; ++i) nbuf[q * 4 + i][ct * 16 + m] = acc[i] + bn;
    __syncthreads();

    float gn = gain[lane];
#pragma unroll
    for (int i = 0; i < 4; ++i) {
        int vloc = ct * 4 + i;
        int vd = d0 + ((vloc >> 3) & 1);
        int vh = h0 + ((vloc >> 2) & 1);
        int vx = x0 + (vloc & 3);
        int w = ((b * G + vd) * G + vh) * G + vx;
        float val = nbuf[vloc][lane];
        float mean = wave_sum64(val) * (1.f / 64.f);
        float dd = val - mean;
        float var = wave_sum64(dd * dd) * (1.f / 64.f) + NEPS;
        float xn = dd * rsqrtf(var);
        float o = fmaxf(gn * (1.f - K_ADA * xn) * xn, 0.f);
        if (mask[w] == 0.f) o = 0.f;
        if (OUTB) outb[(size_t)w * 64 + lane] = f2b(o);
        else      outf[(size_t)w * 64 + lane] = o;
    }
}

// ---- Global max pool stage 1 (h5 >= 0 with zeros at inactive -> plain max) ----
__global__ __launch_bounds__(256) void pool1_k(const float* __restrict__ h5,
                                               float* __restrict__ partials)
{
    int chunk = blockIdx.x % 54;
    int b = blockIdx.x / 54;
    int c = threadIdx.x & 63;
    int s = threadIdx.x >> 6;
    const float* base = h5 + ((size_t)b * 13824 + chunk * 256) * 64;
    float mx = 0.f;
#pragma unroll 4
    for (int v = s; v < 256; v += 4) mx = fmaxf(mx, base[v * 64 + c]);
    __shared__ float red[256];
    red[threadIdx.x] = mx;
    __syncthreads();
    if (s == 0)
        partials[blockIdx.x * 64 + c] =
            fmaxf(fmaxf(red[c], red[64 + c]), fmaxf(red[128 + c], red[192 + c]));
}

// ---- stage 2 + head ----
__global__ __launch_bounds__(128) void pool2_head_k(const float* __restrict__ partials,
                                                    const float* __restrict__ wh,
                                                    const float* __restrict__ bh,
                                                    const float* __restrict__ gh,
                                                    float* __restrict__ out)
{
    __shared__ float pooled[2][64];
    int t = threadIdx.x;
    int b = t >> 6;
    int f = t & 63;
    float mx = 0.f;
    for (int p = 0; p < 54; ++p) mx = fmaxf(mx, partials[(b * 54 + p) * 64 + f]);
    pooled[b][f] = mx;
    __syncthreads();
    float acc = bh[f];
#pragma unroll
    for (int k = 0; k < 64; ++k) acc += pooled[b][k] * wh[k * 64 + f];
    float mean = wave_sum64(acc) * (1.f / 64.f);
    float dd = acc - mean;
    float var = wave_sum64(dd * dd) * (1.f / 64.f) + NEPS;
    float xn = dd * rsqrtf(var);
    float val = gh[f] * (1.f - K_ADA * xn) * xn;
    out[t] = fmaxf(val, 0.f);
}

extern "C" void kernel_launch(void* const* d_in, const int* in_sizes, int n_in,
                              void* d_out, int out_size, void* d_ws, size_t ws_size,
                              hipStream_t stream)
{
    const float* x  = (const float*)d_in[0];
    const float* m1 = (const float*)d_in[1];
    const float* w1 = (const float*)d_in[2];
    const float* b1 = (const float*)d_in[3];
    const float* g1 = (const float*)d_in[4];
    const float* w2 = (const float*)d_in[5];
    const float* b2 = (const float*)d_in[6];
    const float* g2 = (const float*)d_in[7];
    const float* w3 = (const float*)d_in[8];
    const float* b3 = (const float*)d_in[9];
    const float* g3 = (const float*)d_in[10];
    const float* w4 = (const float*)d_in[11];
    const float* b4 = (const float*)d_in[12];
    const float* g4 = (const float*)d_in[13];
    const float* w5 = (const float*)d_in[14];
    const float* b5 = (const float*)d_in[15];
    const float* g5 = (const float*)d_in[16];
    const float* wh = (const float*)d_in[17];
    const float* bh = (const float*)d_in[18];
    const float* gh = (const float*)d_in[19];
    float* out = (float*)d_out;

    // workspace layout (float units; all 16B aligned)
    float* ws = (float*)d_ws;
    ushort_t* h1b = (ushort_t*)ws;                 // 28,311,552 u = 14,155,776 f
    ushort_t* h2b = (ushort_t*)(ws + 14155776);    //  7,077,888 u =  3,538,944 f
    ushort_t* h3b = (ushort_t*)(ws + 17694720);    //  7,077,888 u =  3,538,944 f
    ushort_t* h4b = (ushort_t*)(ws + 21233664);    //  1,769,472 u =    884,736 f
    float* h5 = ws + 22118400;                     //  1,769,472 f
    float* m2 = ws + 23887872;                     //    221,184 f
    float* m3 = ws + 24109056;                     //     27,648 f
    float* partials = ws + 24136704;               //      6,912 f
    ushort_t* wp1 = (ushort_t*)(ws + 24143616);    //     512 u =    256 f
    ushort_t* wp2 = (ushort_t*)(ws + 24143872);    //  14,336 u =  7,168 f
    ushort_t* wp3 = (ushort_t*)(ws + 24151040);    //  27,648 u = 13,824 f
    ushort_t* wp4 = (ushort_t*)(ws + 24164864);    //  55,296 u = 27,648 f
    ushort_t* wp5 = (ushort_t*)(ws + 24192512);    // 110,592 u = 55,296 f
    float* zeropad = ws + 24247808;                //          8 f (32B zero block)

    // prep: weight packs + m1->m2 + zero-pad, one launch; then m2->m3
    prep_k<<<1679, 256, 0, stream>>>(w1, w2, w3, w4, w5, m1,
                                     wp1, wp2, wp3, wp4, wp5, m2, zeropad);
    dmask_k<24, 48><<<108, 256, 0, stream>>>(m2, m3);

    const ushort_t* zp = (const ushort_t*)zeropad;
    // layer 1: MFMA tile conv + fused norm16
    conv1_mfma_k<<<27648, 256, 0, stream>>>(x, m1, wp1, b1, g1, zeropad, h1b);
    // layer 2: MFMA (tap pairs, 32-voxel tiles) + fused norm
    conv2_mfma_k<<<1728, 256, 0, stream>>>(h1b, wp2, b2, g2, m2, zp, h2b);
    // layer 3: MFMA (32-voxel tiles, full unroll) + fused norm
    conv3_mfma_k<<<1728, 256, 0, stream>>>(h2b, wp3, b3, g3, m2, zp, h3b);
    // layer 4: halo-tile LDS implicit GEMM + fused 64-ch norm -> bf16
    conv45_tile_k<48, 32, 2, true><<<1728, 256, 0, stream>>>(h3b, wp4, b4, g4, m3, h4b, nullptr);
    // layer 5: halo-tile LDS implicit GEMM + fused 64-ch norm -> fp32
    conv45_tile_k<24, 64, 1, false><<<1728, 256, 0, stream>>>(h4b, wp5, b5, g5, m3, nullptr, h5);

    // pool + head
    pool1_k<<<108, 256, 0, stream>>>(h5, partials);
    pool2_head_k<<<1, 128, 0, stream>>>(partials, wh, bh, gh, out);
}